// Round 9
// baseline (394.827 us; speedup 1.0000x reference)
//
#include <hip/hip_runtime.h>
#include <hip/hip_fp8.h>
#include <stdint.h>

// (B,T,E,H,D) = (2,2048,1024,16,64)
constexpr float INV_SCALE = 0.022097086912079608f;  // 1/sqrt(2048)
constexpr float LOG2E = 1.4426950408889634f;
constexpr float QSC = INV_SCALE * LOG2E;            // q pre-scale: softmax in exp2 domain

typedef __attribute__((ext_vector_type(8))) short bfrag;          // 8 bf16 (4 VGPR) MFMA frag
typedef __attribute__((ext_vector_type(4))) float facc;           // 4 f32 MFMA acc
typedef __attribute__((ext_vector_type(4))) unsigned short us4;   // 4 bf16 = 8B

#define MFMA(a, b, c) __builtin_amdgcn_mfma_f32_16x16x32_bf16((a), (b), (c), 0, 0, 0)
#define EXP2(x) __builtin_amdgcn_exp2f(x)

__device__ __forceinline__ unsigned short f2bh(float f) {        // f32 -> bf16 RNE
    union { float f; unsigned int u; } cv; cv.f = f;
    unsigned int u = cv.u;
    u += 0x7FFFu + ((u >> 16) & 1u);
    return (unsigned short)(u >> 16);
}
__device__ __forceinline__ float bh2f(unsigned short h) {
    union { unsigned int u; float f; } cv; cv.u = ((unsigned int)h) << 16;
    return cv.f;
}
__device__ __forceinline__ void gl_lds16(const unsigned short* g, unsigned short* lds) {
    // async 16B/lane global->LDS; dst is wave-uniform base, lane i lands at dst+16*i
    __builtin_amdgcn_global_load_lds(
        (const __attribute__((address_space(1))) unsigned int*)g,
        (__attribute__((address_space(3))) unsigned int*)lds, 16, 0, 0);
}
// 8 fp8(e4m3, x256) bytes -> bf16 frag (undo the 256x scale)
__device__ __forceinline__ bfrag f8frag(uint2 raw) {
    union { uint2 u; unsigned char b[8]; } cv; cv.u = raw;
    bfrag r;
    #pragma unroll
    for (int j = 0; j < 8; ++j) {
        const __hip_fp8_e4m3* t = reinterpret_cast<const __hip_fp8_e4m3*>(&cv.b[j]);
        r[j] = (short)f2bh((float)(*t) * 0.00390625f);
    }
    return r;
}

// ---------------------------------------------------------------------------
// prep_xw: fused  Wo fp32->bf16 (blocks 0..1023)  +  x fp32->hi/lo split
// (blocks 1024..5119).
// ---------------------------------------------------------------------------
__global__ __launch_bounds__(256) void prep_xw(const float* __restrict__ x,
                                               const float* __restrict__ Wo,
                                               unsigned short* __restrict__ xh,
                                               unsigned short* __restrict__ xl,
                                               unsigned short* __restrict__ WoB) {
    if (blockIdx.x < 1024) {
        int idx = blockIdx.x * 256 + threadIdx.x;   // f4 index, 262144 total
        facc v = *(const facc*)&Wo[(size_t)idx * 4];
        us4 o;
        #pragma unroll
        for (int j = 0; j < 4; ++j) o[j] = f2bh(v[j]);
        *(us4*)&WoB[(size_t)idx * 4] = o;
    } else {
        int idx = (blockIdx.x - 1024) * 256 + threadIdx.x;  // f4 idx, 1,048,576 total
        facc v = *(const facc*)&x[(size_t)idx * 4];
        us4 hv, lv;
        #pragma unroll
        for (int j = 0; j < 4; ++j) {
            unsigned short hb = f2bh(v[j]);
            hv[j] = hb;
            lv[j] = f2bh(v[j] - bh2f(hb));
        }
        *(us4*)&xh[(size_t)idx * 4] = hv;
        *(us4*)&xl[(size_t)idx * 4] = lv;
    }
}

// ---------------------------------------------------------------------------
// prep_w: per head, transpose W[h][1024 e][64 i] -> WT[h*64+i][1024 e] with
// hi/lo bf16 split for Wq/Wk, hi-only for Wv.  grid (16,16,3), block 256.
// ---------------------------------------------------------------------------
__global__ __launch_bounds__(256) void prep_w(
    const float* __restrict__ Wq, const float* __restrict__ Wk, const float* __restrict__ Wv,
    unsigned short* __restrict__ WqTh, unsigned short* __restrict__ WqTl,
    unsigned short* __restrict__ WkTh, unsigned short* __restrict__ WkTl,
    unsigned short* __restrict__ WvT)
{
    __shared__ float tile[64][65];
    const int tid = threadIdx.x;
    const int et = blockIdx.x, h = blockIdx.y, m = blockIdx.z;
    const float* W = (m == 0) ? Wq : (m == 1) ? Wk : Wv;
    #pragma unroll
    for (int rep = 0; rep < 4; ++rep) {
        int idx = rep * 256 + tid;            // f4 idx over [64e][16 i4]
        int e = idx >> 4, i4 = (idx & 15) * 4;
        facc v = *(const facc*)&W[(size_t)h * 65536 + (size_t)(et * 64 + e) * 64 + i4];
        tile[e][i4] = v.x; tile[e][i4 + 1] = v.y; tile[e][i4 + 2] = v.z; tile[e][i4 + 3] = v.w;
    }
    __syncthreads();
    unsigned short* Oh = (m == 0) ? WqTh : (m == 1) ? WkTh : WvT;
    unsigned short* Ol = (m == 0) ? WqTl : WkTl;   // unused when m==2
    #pragma unroll
    for (int rep = 0; rep < 4; ++rep) {
        int idx = rep * 256 + tid;            // [64 i][16 e4]
        int i = idx >> 4, e4 = (idx & 15) * 4;
        us4 hv, lv;
        #pragma unroll
        for (int j = 0; j < 4; ++j) {
            float f = tile[e4 + j][i];
            unsigned short hb = f2bh(f);
            hv[j] = hb;
            lv[j] = f2bh(f - bh2f(hb));
        }
        size_t o = (size_t)(h * 64 + i) * 1024 + et * 64 + e4;
        *(us4*)&Oh[o] = hv;
        if (m < 2) *(us4*)&Ol[o] = lv;
    }
}

// ---------------------------------------------------------------------------
// qkv_fused: block (ct, rt) computes q,k,v for rows [rt*128,+128), cols
// [ct*128,+128) in one K=1024 pass.  8 waves (2x4).  A staged once, reused.
// Counted-vmcnt pipeline (see R6).  grid (8, 32) = 256 blocks = 1/CU.
// v output goes to the FRAGMENT-MAJOR vF layout consumed by attn:
// vF[(hb*32+kt)*8 + s*4+f][lane][8] with lane=(d&15)|((c&3)<<4), c=s*4+(lane>>4).
// ---------------------------------------------------------------------------
__global__ __launch_bounds__(512, 2) void qkv_fused(
    const unsigned short* __restrict__ xh, const unsigned short* __restrict__ xl,
    const unsigned short* __restrict__ WqTh, const unsigned short* __restrict__ WqTl,
    const unsigned short* __restrict__ WkTh, const unsigned short* __restrict__ WkTl,
    const unsigned short* __restrict__ WvT,
    unsigned short* __restrict__ qh, unsigned char* __restrict__ ql8,
    unsigned short* __restrict__ kh, unsigned short* __restrict__ kl,
    unsigned short* __restrict__ vF)
{
    extern __shared__ unsigned short sm[];
    unsigned short* Ab = sm;               // [2][128*64] 32KB
    unsigned short* Qb = sm + 16384;       // 32KB
    unsigned short* Kb = sm + 32768;       // 32KB
    unsigned short* Vb = sm + 49152;       // 32KB
    const int tid = threadIdx.x;
    const int w = tid >> 6, l = tid & 63;
    const int wm = w >> 2, wn = w & 3;     // 2 x 4 wave grid
    const int ct = blockIdx.x, rt = blockIdx.y;

    const int lc = (l & 7) ^ (l >> 3);
    const int krel = (lc & 3) * 8;
    const unsigned short* Axp = (lc < 4) ? xh : xl;
    const unsigned short* Qp  = (lc < 4) ? WqTh : WqTl;
    const unsigned short* Kp  = (lc < 4) ? WkTh : WkTl;

    facc accq[4][2], acck[4][2], accv[4][2];
    #pragma unroll
    for (int m = 0; m < 4; ++m)
        #pragma unroll
        for (int n = 0; n < 2; ++n) {
            accq[m][n] = (facc)(0.0f); acck[m][n] = (facc)(0.0f); accv[m][n] = (facc)(0.0f);
        }

    auto stageAB = [&](int buf, int e0) {
        #pragma unroll
        for (int i = 0; i < 2; ++i) {
            int slice = w * 2 + i;                   // 0..15
            int row = slice * 8 + (l >> 3);
            size_t sa = (size_t)(rt * 128 + row) * 1024 + e0 + krel;
            size_t sb = (size_t)(ct * 128 + row) * 1024 + e0 + krel;
            gl_lds16(&Axp[sa], &Ab[buf * 8192 + slice * 512]);
            gl_lds16(&Qp[sb],  &Qb[buf * 8192 + slice * 512]);
            gl_lds16(&Kp[sb],  &Kb[buf * 8192 + slice * 512]);
        }
    };

    stageAB(0, 0);
    #pragma unroll
    for (int i = 0; i < 2; ++i) {
        int slice = w * 2 + i;
        int row = slice * 8 + (l >> 3);
        gl_lds16(&WvT[(size_t)(ct * 128 + row) * 1024 + lc * 8], &Vb[slice * 512]);
    }
    asm volatile("s_waitcnt vmcnt(0)" ::: "memory");
    __builtin_amdgcn_s_barrier();

    for (int t = 0; t < 32; ++t) {
        __builtin_amdgcn_s_barrier();              // bar1: all done with t-1 compute
        __builtin_amdgcn_sched_barrier(0);
        if (t < 31) stageAB((t + 1) & 1, (t + 1) * 32);      // 6 loads/wave
        {   // half of v window (t>>1)+1 : 1 load/wave (t <= 29)
            int wv = (t >> 1) + 1;
            if (wv < 16) {
                int slice = w + (t & 1) * 8;
                int row = slice * 8 + (l >> 3);
                gl_lds16(&WvT[(size_t)(ct * 128 + row) * 1024 + wv * 64 + lc * 8],
                         &Vb[(wv & 1) * 8192 + slice * 512]);
            }
        }
        __builtin_amdgcn_sched_barrier(0);
        if (t < 30)       asm volatile("s_waitcnt vmcnt(7)" ::: "memory");
        else if (t == 30) asm volatile("s_waitcnt vmcnt(6)" ::: "memory");
        else              asm volatile("s_waitcnt vmcnt(0)" ::: "memory");
        __builtin_amdgcn_sched_barrier(0);
        __builtin_amdgcn_s_barrier();              // bar2: everyone's cur loads landed
        __builtin_amdgcn_sched_barrier(0);

        const unsigned short* Ac = &Ab[(t & 1) * 8192];
        const unsigned short* Qc = &Qb[(t & 1) * 8192];
        const unsigned short* Kc = &Kb[(t & 1) * 8192];
        const unsigned short* Vc = &Vb[((t >> 1) & 1) * 8192];
        const int ca = (l >> 4) ^ (l & 7);         // phys chunk of hi frag
        const int cb = ca ^ 4;                     // lo frag
        const int cv = ca ^ ((t & 1) << 2);        // v frag (window parity)

        bfrag afh[4], afl[4];
        #pragma unroll
        for (int m = 0; m < 4; ++m) {
            int row = wm * 64 + m * 16 + (l & 15);
            afh[m] = *(const bfrag*)&Ac[row * 64 + ca * 8];
            afl[m] = *(const bfrag*)&Ac[row * 64 + cb * 8];
        }
        #pragma unroll
        for (int n = 0; n < 2; ++n) {
            int nr = wn * 32 + n * 16 + (l & 15);
            bfrag bv = *(const bfrag*)&Vc[nr * 64 + cv * 8];
            #pragma unroll
            for (int m = 0; m < 4; ++m) accv[m][n] = MFMA(afh[m], bv, accv[m][n]);
        }
        #pragma unroll
        for (int n = 0; n < 2; ++n) {
            int nr = wn * 32 + n * 16 + (l & 15);
            bfrag bh = *(const bfrag*)&Qc[nr * 64 + ca * 8];
            bfrag bl = *(const bfrag*)&Qc[nr * 64 + cb * 8];
            #pragma unroll
            for (int m = 0; m < 4; ++m) {
                accq[m][n] = MFMA(afh[m], bh, accq[m][n]);
                accq[m][n] = MFMA(afh[m], bl, accq[m][n]);
                accq[m][n] = MFMA(afl[m], bh, accq[m][n]);
            }
        }
        #pragma unroll
        for (int n = 0; n < 2; ++n) {
            int nr = wn * 32 + n * 16 + (l & 15);
            bfrag bh = *(const bfrag*)&Kc[nr * 64 + ca * 8];
            bfrag bl = *(const bfrag*)&Kc[nr * 64 + cb * 8];
            #pragma unroll
            for (int m = 0; m < 4; ++m) {
                acck[m][n] = MFMA(afh[m], bh, acck[m][n]);
                acck[m][n] = MFMA(afh[m], bl, acck[m][n]);
                acck[m][n] = MFMA(afl[m], bh, acck[m][n]);
            }
        }
    }

    // epilogue
    #pragma unroll
    for (int m = 0; m < 4; ++m)
        #pragma unroll
        for (int r = 0; r < 4; ++r) {
            int row = rt * 128 + wm * 64 + m * 16 + (l >> 4) * 4 + r;
            #pragma unroll
            for (int n = 0; n < 2; ++n) {
                int col = ct * 128 + wn * 32 + n * 16 + (l & 15);
                float fq = accq[m][n][r] * QSC;
                unsigned short hb = f2bh(fq);
                qh[(size_t)row * 1024 + col] = hb;
                __hip_fp8_e4m3 e((fq - bh2f(hb)) * 256.0f);
                ql8[(size_t)row * 1024 + col] = *reinterpret_cast<unsigned char*>(&e);
                float fk = acck[m][n][r];
                unsigned short kb = f2bh(fk);
                kh[(size_t)row * 1024 + col] = kb;
                kl[(size_t)row * 1024 + col] = f2bh(fk - bh2f(kb));
            }
        }
    // v -> fragment-major vF
    #pragma unroll
    for (int m = 0; m < 4; ++m) {
        int t0g = rt * 128 + wm * 64 + m * 16 + (l >> 4) * 4;
        int b_ = t0g >> 11, t0 = t0g & 2047;
        int kt = t0 >> 6, tin = t0 & 63;
        int c = tin >> 3, s = c >> 2;                 // chunk 0..7, s-half
        #pragma unroll
        for (int n = 0; n < 2; ++n) {
            int col = ct * 128 + wn * 32 + n * 16 + (l & 15);
            int h_ = col >> 6, d = col & 63;
            int f = d >> 4;
            int lane_v = (d & 15) | ((c & 3) << 4);
            us4 pk;
            #pragma unroll
            for (int r = 0; r < 4; ++r) pk[r] = f2bh(accv[m][n][r]);
            size_t off = (((size_t)(h_ * 2 + b_) * 32 + kt) * 8 + s * 4 + f) * 512
                         + lane_v * 8 + (tin & 7);
            *(us4*)&vF[off] = pk;
        }
    }
}

// ---------------------------------------------------------------------------
// attn helpers
// ---------------------------------------------------------------------------
__device__ __forceinline__ void stage_k(
    const unsigned short* __restrict__ kh, const unsigned short* __restrict__ kl,
    unsigned short* Khb, unsigned short* Klb, int w, int l, int b, int h, int kt)
{
    #pragma unroll
    for (int i = 0; i < 2; ++i) {
        int pbase = (w * 2 + i) * 1024;    // uniform 1KB slice base (bytes)
        int p = pbase + l * 16;
        int row = p >> 7, slot = (p >> 4) & 7;
        int chunk = slot ^ (row & 7);      // inverse-swizzled source chunk
        size_t srcK = (size_t)(b * 2048 + kt * 64 + row) * 1024 + h * 64 + chunk * 8;
        gl_lds16(&kh[srcK], &Khb[pbase >> 1]);
        gl_lds16(&kl[srcK], &Klb[pbase >> 1]);
    }
}

__device__ __forceinline__ void qkt_tile(
    const unsigned short* Khc, const unsigned short* Klc,
    const bfrag* qfh, const bfrag* qfl, facc* S, int l)
{
    #pragma unroll
    for (int f = 0; f < 4; ++f) S[f] = (facc)(0.0f);
    #pragma unroll
    for (int s = 0; s < 2; ++s) {
        #pragma unroll
        for (int f = 0; f < 4; ++f) {
            int key = f * 16 + (l & 15);
            int ch = (s * 4 + (l >> 4)) ^ (key & 7);
            bfrag kbh = *(const bfrag*)&Khc[key * 64 + ch * 8];
            bfrag kbl = *(const bfrag*)&Klc[key * 64 + ch * 8];
            S[f] = MFMA(qfh[s], kbh, S[f]);
            S[f] = MFMA(qfh[s], kbl, S[f]);
            S[f] = MFMA(qfl[s], kbh, S[f]);
        }
    }
}

__device__ __forceinline__ void causal_mask(facc* S, int w, int l) {
    #pragma unroll
    for (int f = 0; f < 4; ++f) {
        int keyl = f * 16 + (l & 15);
        #pragma unroll
        for (int r = 0; r < 4; ++r) {
            int qls = w * 16 + (l >> 4) * 4 + r;
            if (keyl > qls) S[f][r] = -1e30f;
        }
    }
}

// softmax (exp2 domain, defer-max THR=8) + P write.  NO sum reduction --
// the denominator comes from the ones-MFMA in pv().
__device__ __forceinline__ void softmax_pw(
    facc* S, float* mrow, facc* O, facc& Osum, unsigned short* Pl, int w, int l)
{
    float mx[4];
    float dmax = -3.0e38f;
    #pragma unroll
    for (int r = 0; r < 4; ++r) {
        float m0 = fmaxf(fmaxf(S[0][r], S[1][r]), fmaxf(S[2][r], S[3][r]));
        m0 = fmaxf(m0, __shfl_xor(m0, 1));
        m0 = fmaxf(m0, __shfl_xor(m0, 2));
        m0 = fmaxf(m0, __shfl_xor(m0, 4));
        m0 = fmaxf(m0, __shfl_xor(m0, 8));
        mx[r] = m0;
        dmax = fmaxf(dmax, m0 - mrow[r]);
    }
    if (!__all(dmax <= 8.0f)) {            // wave-uniform rescale (rare)
        #pragma unroll
        for (int r = 0; r < 4; ++r) {
            float mn = fmaxf(mrow[r], mx[r]);
            float fac = EXP2(mrow[r] - mn);
            mrow[r] = mn;
            O[0][r] *= fac; O[1][r] *= fac; O[2][r] *= fac; O[3][r] *= fac;
            Osum[r] *= fac;
        }
    }
    #pragma unroll
    for (int r = 0; r < 4; ++r)
        #pragma unroll
        for (int f = 0; f < 4; ++f) S[f][r] = EXP2(S[f][r] - mrow[r]);
    #pragma unroll
    for (int f = 0; f < 4; ++f) {
        int key = f * 16 + (l & 15);
        #pragma unroll
        for (int r = 0; r < 4; ++r) {
            int qr = w * 16 + (l >> 4) * 4 + r;
            Pl[qr * 64 + (((key >> 3) ^ (qr & 7)) * 8) + (key & 7)] = f2bh(S[f][r]);
        }
    }
}

// PV from register V frags + ones-MFMA row-sum accumulation.
__device__ __forceinline__ void pv(
    const bfrag* vf, const unsigned short* Pl, facc* O, facc& Osum,
    bfrag ones, int w, int l)
{
    #pragma unroll
    for (int s = 0; s < 2; ++s) {
        int qa = w * 16 + (l & 15);
        int cha = (s * 4 + (l >> 4)) ^ (qa & 7);
        bfrag pa = *(const bfrag*)&Pl[qa * 64 + cha * 8];
        Osum = MFMA(pa, ones, Osum);
        #pragma unroll
        for (int f = 0; f < 4; ++f)
            O[f] = MFMA(pa, vf[s * 4 + f], O[f]);
    }
}

// ---------------------------------------------------------------------------
// attn_mfma: paired-q-tile flash attention, 2-deep pipelined.  grid (16, 32),
// block 256 (4 waves), 40KB static LDS.  Per step kt: QK^T(kt+1) MFMAs issue
// under softmax(kt)'s VALU chain; V frags come straight from global (L2) in
// fragment-major layout; row sums via ones-MFMA.  K staged 2 ahead, one
// __syncthreads per step (drains prior-step loads; WAR-protects buffers).
// ---------------------------------------------------------------------------
__global__ __launch_bounds__(256, 2) void attn_mfma(
    const unsigned short* __restrict__ qh, const unsigned char* __restrict__ ql8,
    const unsigned short* __restrict__ kh, const unsigned short* __restrict__ kl,
    const unsigned short* __restrict__ vF, unsigned short* __restrict__ att)
{
    __shared__ unsigned short Kh[2][4096], Kl[2][4096], Pl[4096];
    const int tid = threadIdx.x, w = tid >> 6, l = tid & 63;
    const int dd = blockIdx.y * 16 + blockIdx.x;
    const int xcd = dd & 7, sl = dd >> 3;
    const int hb = xcd * 4 + (sl >> 4);
    const int bx = sl & 15;
    const int qtA = 31 - bx, qtB = bx;     // qtA >= 16 > qtB always
    const int h = hb >> 1, b = hb & 1;
    const unsigned short* vFb = vF + (size_t)hb * 32 * 8 * 512;

    bfrag ones;
    #pragma unroll
    for (int j = 0; j < 8; ++j) ones[j] = (short)0x3F80;   // bf16 1.0

    bfrag qfhA[2], qflA[2], qfhB[2], qflB[2];
    {
        const int qrowA = qtA * 64 + w * 16 + (l & 15);
        const size_t qoffA = (size_t)(b * 2048 + qrowA) * 1024 + h * 64 + (l >> 4) * 8;
        qfhA[0] = *(const bfrag*)&qh[qoffA];
        qfhA[1] = *(const bfrag*)&qh[qoffA + 32];
        qflA[0] = f8frag(*(const uint2*)&ql8[qoffA]);
        qflA[1] = f8frag(*(const uint2*)&ql8[qoffA + 32]);
        const int qrowB = qtB * 64 + w * 16 + (l & 15);
        const size_t qoffB = (size_t)(b * 2048 + qrowB) * 1024 + h * 64 + (l >> 4) * 8;
        qfhB[0] = *(const bfrag*)&qh[qoffB];
        qfhB[1] = *(const bfrag*)&qh[qoffB + 32];
        qflB[0] = f8frag(*(const uint2*)&ql8[qoffB]);
        qflB[1] = f8frag(*(const uint2*)&ql8[qoffB + 32]);
    }

    facc OA[4], OB[4], OsA, OsB;
    float mA[4], mB[4];
    #pragma unroll
    for (int f = 0; f < 4; ++f) { OA[f] = (facc)(0.0f); OB[f] = (facc)(0.0f); }
    OsA = (facc)(0.0f); OsB = (facc)(0.0f);
    #pragma unroll
    for (int r = 0; r < 4; ++r) { mA[r] = -1e30f; mB[r] = -1e30f; }

    facc S0A[4], S0B[4], S1A[4], S1B[4];

    // prologue: K(0), K(1) staged; compute S(0)
    stage_k(kh, kl, Kh[0], Kl[0], w, l, b, h, 0);
    stage_k(kh, kl, Kh[1], Kl[1], w, l, b, h, 1);
    __syncthreads();
    qkt_tile(Kh[0], Kl[0], qfhA, qflA, S0A, l);
    qkt_tile(Kh[0], Kl[0], qfhB, qflB, S0B, l);
    if (qtB == 0) causal_mask(S0B, w, l);

    auto step = [&](int kt, facc* ScA, facc* ScB, facc* SnA, facc* SnB) {
        __syncthreads();                    // drains K(kt+1) loads; WAR on buffers
        // V(kt) frags direct from global (fragment-major, coalesced, L2-hit)
        bfrag vf[8];
        {
            const unsigned short* vb = vFb + (size_t)kt * 4096 + l * 8;
            #pragma unroll
            for (int i = 0; i < 8; ++i)
                vf[i] = *(const bfrag*)&vb[i * 512];
        }
        if (kt + 2 <= qtA)
            stage_k(kh, kl, Kh[kt & 1], Kl[kt & 1], w, l, b, h, kt + 2);
        // next-step QK^T (independent of this step's softmax -> overlaps)
        if (kt + 1 <= qtA) {
            qkt_tile(Kh[(kt + 1) & 1], Kl[(kt + 1) & 1], qfhA, qflA, SnA, l);
            if (kt + 1 == qtA) causal_mask(SnA, w, l);
        }
        if (kt + 1 <= qtB) {
            qkt_tile(Kh[(kt + 1) & 1], Kl[(kt + 1) & 1], qfhB, qflB, SnB, l);
            if (kt + 1 == qtB) causal_mask(SnB, w, l);
        }
        // current-step softmax + PV
        softmax_pw(ScA, mA, OA, OsA, Pl, w, l);
        pv(vf, Pl, OA, OsA, ones, w, l);
        if (kt <= qtB) {
            softmax_pw(ScB, mB, OB, OsB, Pl, w, l);
            pv(vf, Pl, OB, OsB, ones, w, l);
        }
    };

    for (int kt = 0; kt <= qtA; ++kt) {
        if (kt & 1) step(kt, S1A, S1B, S0A, S0B);
        else        step(kt, S0A, S0B, S1A, S1B);
    }

    #pragma unroll
    for (int f = 0; f < 4; ++f) {
        int d = h * 64 + f * 16 + (l & 15);
        #pragma unroll
        for (int r = 0; r < 4; ++r) {
            int tA = qtA * 64 + w * 16 + (l >> 4) * 4 + r;
            att[(size_t)(b * 2048 + tA) * 1024 + d] = f2bh(OA[f][r] / OsA[r]);
            int tB = qtB * 64 + w * 16 + (l >> 4) * 4 + r;
            att[(size_t)(b * 2048 + tB) * 1024 + d] = f2bh(OB[f][r] / OsB[r]);
        }
    }
}

// ---------------------------------------------------------------------------
// outproj: out[4096,1024] = att @ Wo^T.  BK=64 swizzled, double-buffered with
// the prefetch-across-raw-barrier loop.  grid (32, 8), 64KB LDS.
// ---------------------------------------------------------------------------
__global__ __launch_bounds__(256, 2) void outproj(
    const unsigned short* __restrict__ att, const unsigned short* __restrict__ WoB,
    float* __restrict__ out)
{
    __shared__ unsigned short Ab[2][128 * 64], Bb[2][128 * 64];
    const int tid = threadIdx.x, w = tid >> 6, l = tid & 63;
    const int wm = w >> 1, wn = w & 1;
    const int rt = blockIdx.x, ct = blockIdx.y;

    const int lc = (l & 7) ^ (l >> 3);         // logical chunk (0..7) -> k-offset lc*8
    facc acc[4][4];
    #pragma unroll
    for (int i = 0; i < 4; ++i)
        #pragma unroll
        for (int j = 0; j < 4; ++j) acc[i][j] = (facc)(0.0f);

    auto stage = [&](int buf, int e0) {
        #pragma unroll
        for (int i = 0; i < 4; ++i) {
            int slice = w * 4 + i;
            int row = slice * 8 + (l >> 3);
            gl_lds16(&att[(size_t)(rt * 128 + row) * 1024 + e0 + lc * 8], &Ab[buf][slice * 512]);
            gl_lds16(&WoB[(size_t)(ct * 128 + row) * 1024 + e0 + lc * 8], &Bb[buf][slice * 512]);
        }
    };

    stage(0, 0);
    int cur = 0;
    for (int t = 0; t < 16; ++t) {
        __syncthreads();
        if (t < 15) stage(cur ^ 1, (t + 1) * 64);
        __builtin_amdgcn_sched_barrier(0);
        __builtin_amdgcn_s_barrier();
        __builtin_amdgcn_sched_barrier(0);
        #pragma unroll
        for (int s = 0; s < 2; ++s) {
            const int slot = (s * 4 + (l >> 4)) ^ (l & 7);
            bfrag af[4], bf_[4];
            #pragma unroll
            for (int m = 0; m < 4; ++m)
                af[m] = *(const bfrag*)&Ab[cur][(wm * 64 + m * 16 + (l & 15)) * 64 + slot * 8];
            #pragma unroll
            for (int n = 0; n < 4; ++n)
                bf_[n] = *(const bfrag*)&Bb[cur][(wn * 64 + n * 16 + (l & 15)) * 64 + slot * 8];
            #pragma unroll
            for (int m = 0; m < 4; ++m)
                #pragma unroll
                for (int n = 0; n < 4; ++n)
                    acc[m][n] = MFMA(af[m], bf_[n], acc[m][n]);
        }
        cur ^= 1;
    }
    #pragma unroll
    for (int m = 0; m < 4; ++m)
        #pragma unroll
        for (int r = 0; r < 4; ++r) {
            int row = rt * 128 + wm * 64 + m * 16 + (l >> 4) * 4 + r;
            #pragma unroll
            for (int n = 0; n < 4; ++n) {
                int col = ct * 128 + wn * 64 + n * 16 + (l & 15);
                out[(size_t)row * 1024 + col] = acc[m][n][r];
            }
        }
}

// ---------------------------------------------------------------------------
extern "C" void kernel_launch(void* const* d_in, const int* in_sizes, int n_in,
                              void* d_out, int out_size, void* d_ws, size_t ws_size,
                              hipStream_t stream) {
    const float* x  = (const float*)d_in[0];
    // d_in[1]: causal mask (applied analytically)
    const float* Wq = (const float*)d_in[2];
    const float* Wk = (const float*)d_in[3];
    const float* Wv = (const float*)d_in[4];
    const float* Wo = (const float*)d_in[5];

    uint8_t* wsb = (uint8_t*)d_ws;
    const size_t MB = 1024 * 1024;
    // 64MB layout.  xh overlays att (xh dead before attn writes att).
    unsigned short* WqTh = (unsigned short*)(wsb + 0 * MB);
    unsigned short* WqTl = (unsigned short*)(wsb + 2 * MB);
    unsigned short* WkTh = (unsigned short*)(wsb + 4 * MB);
    unsigned short* WkTl = (unsigned short*)(wsb + 6 * MB);
    unsigned short* WvT  = (unsigned short*)(wsb + 8 * MB);
    unsigned short* qh   = (unsigned short*)(wsb + 10 * MB);  // 8MB
    unsigned char*  ql8  = (unsigned char*)(wsb + 18 * MB);   // 4MB fp8
    unsigned short* kh   = (unsigned short*)(wsb + 22 * MB);  // 8MB
    unsigned short* kl   = (unsigned short*)(wsb + 30 * MB);  // 8MB
    unsigned short* vF   = (unsigned short*)(wsb + 38 * MB);  // 8MB (fragment-major)
    unsigned short* att  = (unsigned short*)(wsb + 46 * MB);  // 8MB
    unsigned short* xh   = (unsigned short*)(wsb + 46 * MB);  // 8MB (alias att)
    unsigned short* WoB  = (unsigned short*)(wsb + 54 * MB);  // 2MB
    unsigned short* xl   = (unsigned short*)(wsb + 56 * MB);  // 8MB

    hipFuncSetAttribute((const void*)qkv_fused,
                        hipFuncAttributeMaxDynamicSharedMemorySize, 131072);

    prep_xw<<<dim3(5120), 256, 0, stream>>>(x, Wo, xh, xl, WoB);
    prep_w<<<dim3(16, 16, 3), 256, 0, stream>>>(Wq, Wk, Wv, WqTh, WqTl, WkTh, WkTl, WvT);
    qkv_fused<<<dim3(8, 32), 512, 131072, stream>>>(xh, xl, WqTh, WqTl, WkTh, WkTl, WvT,
                                                    qh, ql8, kh, kl, vF);
    attn_mfma<<<dim3(16, 32), 256, 0, stream>>>(qh, ql8, kh, kl, vF, att);
    outproj<<<dim3(32, 8), 256, 0, stream>>>(att, WoB, (float*)d_out);
}

// Round 10
// 167.875 us; speedup vs baseline: 2.3519x; 2.3519x over previous
//
#include <hip/hip_runtime.h>
#include <hip/hip_fp8.h>
#include <stdint.h>

// (B,T,E,H,D) = (2,2048,1024,16,64)
constexpr float INV_SCALE = 0.022097086912079608f;  // 1/sqrt(2048)
constexpr float LOG2E = 1.4426950408889634f;
constexpr float QSC = INV_SCALE * LOG2E;            // q pre-scale: softmax in exp2 domain

typedef __attribute__((ext_vector_type(8))) short bfrag;          // 8 bf16 (4 VGPR) MFMA frag
typedef __attribute__((ext_vector_type(4))) float facc;           // 4 f32 MFMA acc
typedef __attribute__((ext_vector_type(4))) unsigned short us4;   // 4 bf16 = 8B

#define MFMA(a, b, c) __builtin_amdgcn_mfma_f32_16x16x32_bf16((a), (b), (c), 0, 0, 0)
#define EXP2(x) __builtin_amdgcn_exp2f(x)

__device__ __forceinline__ unsigned short f2bh(float f) {        // f32 -> bf16 RNE
    union { float f; unsigned int u; } cv; cv.f = f;
    unsigned int u = cv.u;
    u += 0x7FFFu + ((u >> 16) & 1u);
    return (unsigned short)(u >> 16);
}
__device__ __forceinline__ float bh2f(unsigned short h) {
    union { unsigned int u; float f; } cv; cv.u = ((unsigned int)h) << 16;
    return cv.f;
}
__device__ __forceinline__ void gl_lds16(const unsigned short* g, unsigned short* lds) {
    // async 16B/lane global->LDS; dst is wave-uniform base, lane i lands at dst+16*i
    __builtin_amdgcn_global_load_lds(
        (const __attribute__((address_space(1))) unsigned int*)g,
        (__attribute__((address_space(3))) unsigned int*)lds, 16, 0, 0);
}
// 8 fp8(e4m3, x256) bytes -> bf16 frag (undo the 256x scale)
__device__ __forceinline__ bfrag f8frag(uint2 raw) {
    union { uint2 u; unsigned char b[8]; } cv; cv.u = raw;
    bfrag r;
    #pragma unroll
    for (int j = 0; j < 8; ++j) {
        const __hip_fp8_e4m3* t = reinterpret_cast<const __hip_fp8_e4m3*>(&cv.b[j]);
        r[j] = (short)f2bh((float)(*t) * 0.00390625f);
    }
    return r;
}

// ---------------------------------------------------------------------------
// prep_xw: fused  Wo fp32->bf16 (blocks 0..1023)  +  x fp32->hi/lo split
// (blocks 1024..5119).
// ---------------------------------------------------------------------------
__global__ __launch_bounds__(256) void prep_xw(const float* __restrict__ x,
                                               const float* __restrict__ Wo,
                                               unsigned short* __restrict__ xh,
                                               unsigned short* __restrict__ xl,
                                               unsigned short* __restrict__ WoB) {
    if (blockIdx.x < 1024) {
        int idx = blockIdx.x * 256 + threadIdx.x;   // f4 index, 262144 total
        facc v = *(const facc*)&Wo[(size_t)idx * 4];
        us4 o;
        #pragma unroll
        for (int j = 0; j < 4; ++j) o[j] = f2bh(v[j]);
        *(us4*)&WoB[(size_t)idx * 4] = o;
    } else {
        int idx = (blockIdx.x - 1024) * 256 + threadIdx.x;  // f4 idx, 1,048,576 total
        facc v = *(const facc*)&x[(size_t)idx * 4];
        us4 hv, lv;
        #pragma unroll
        for (int j = 0; j < 4; ++j) {
            unsigned short hb = f2bh(v[j]);
            hv[j] = hb;
            lv[j] = f2bh(v[j] - bh2f(hb));
        }
        *(us4*)&xh[(size_t)idx * 4] = hv;
        *(us4*)&xl[(size_t)idx * 4] = lv;
    }
}

// ---------------------------------------------------------------------------
// prep_w: per head, transpose W[h][1024 e][64 i] -> WT[h*64+i][1024 e] with
// hi/lo bf16 split for Wq/Wk, hi-only for Wv.  grid (16,16,3), block 256.
// ---------------------------------------------------------------------------
__global__ __launch_bounds__(256) void prep_w(
    const float* __restrict__ Wq, const float* __restrict__ Wk, const float* __restrict__ Wv,
    unsigned short* __restrict__ WqTh, unsigned short* __restrict__ WqTl,
    unsigned short* __restrict__ WkTh, unsigned short* __restrict__ WkTl,
    unsigned short* __restrict__ WvT)
{
    __shared__ float tile[64][65];
    const int tid = threadIdx.x;
    const int et = blockIdx.x, h = blockIdx.y, m = blockIdx.z;
    const float* W = (m == 0) ? Wq : (m == 1) ? Wk : Wv;
    #pragma unroll
    for (int rep = 0; rep < 4; ++rep) {
        int idx = rep * 256 + tid;            // f4 idx over [64e][16 i4]
        int e = idx >> 4, i4 = (idx & 15) * 4;
        facc v = *(const facc*)&W[(size_t)h * 65536 + (size_t)(et * 64 + e) * 64 + i4];
        tile[e][i4] = v.x; tile[e][i4 + 1] = v.y; tile[e][i4 + 2] = v.z; tile[e][i4 + 3] = v.w;
    }
    __syncthreads();
    unsigned short* Oh = (m == 0) ? WqTh : (m == 1) ? WkTh : WvT;
    unsigned short* Ol = (m == 0) ? WqTl : WkTl;   // unused when m==2
    #pragma unroll
    for (int rep = 0; rep < 4; ++rep) {
        int idx = rep * 256 + tid;            // [64 i][16 e4]
        int i = idx >> 4, e4 = (idx & 15) * 4;
        us4 hv, lv;
        #pragma unroll
        for (int j = 0; j < 4; ++j) {
            float f = tile[e4 + j][i];
            unsigned short hb = f2bh(f);
            hv[j] = hb;
            lv[j] = f2bh(f - bh2f(hb));
        }
        size_t o = (size_t)(h * 64 + i) * 1024 + et * 64 + e4;
        *(us4*)&Oh[o] = hv;
        if (m < 2) *(us4*)&Ol[o] = lv;
    }
}

// ---------------------------------------------------------------------------
// qkv_fused: block (ct, rt) computes q,k,v for rows [rt*128,+128), cols
// [ct*128,+128) in one K=1024 pass.  8 waves (2x4).  A staged once, reused.
// Counted-vmcnt pipeline.  grid (8, 32) = 256 blocks = 1/CU.
// ---------------------------------------------------------------------------
__global__ __launch_bounds__(512, 2) void qkv_fused(
    const unsigned short* __restrict__ xh, const unsigned short* __restrict__ xl,
    const unsigned short* __restrict__ WqTh, const unsigned short* __restrict__ WqTl,
    const unsigned short* __restrict__ WkTh, const unsigned short* __restrict__ WkTl,
    const unsigned short* __restrict__ WvT,
    unsigned short* __restrict__ qh, unsigned char* __restrict__ ql8,
    unsigned short* __restrict__ kh, unsigned short* __restrict__ kl,
    unsigned short* __restrict__ vT)
{
    extern __shared__ unsigned short sm[];
    unsigned short* Ab = sm;               // [2][128*64] 32KB
    unsigned short* Qb = sm + 16384;       // 32KB
    unsigned short* Kb = sm + 32768;       // 32KB
    unsigned short* Vb = sm + 49152;       // 32KB
    const int tid = threadIdx.x;
    const int w = tid >> 6, l = tid & 63;
    const int wm = w >> 2, wn = w & 3;     // 2 x 4 wave grid
    const int ct = blockIdx.x, rt = blockIdx.y;

    const int lc = (l & 7) ^ (l >> 3);
    const int krel = (lc & 3) * 8;
    const unsigned short* Axp = (lc < 4) ? xh : xl;
    const unsigned short* Qp  = (lc < 4) ? WqTh : WqTl;
    const unsigned short* Kp  = (lc < 4) ? WkTh : WkTl;

    facc accq[4][2], acck[4][2], accv[4][2];
    #pragma unroll
    for (int m = 0; m < 4; ++m)
        #pragma unroll
        for (int n = 0; n < 2; ++n) {
            accq[m][n] = (facc)(0.0f); acck[m][n] = (facc)(0.0f); accv[m][n] = (facc)(0.0f);
        }

    auto stageAB = [&](int buf, int e0) {
        #pragma unroll
        for (int i = 0; i < 2; ++i) {
            int slice = w * 2 + i;                   // 0..15
            int row = slice * 8 + (l >> 3);
            size_t sa = (size_t)(rt * 128 + row) * 1024 + e0 + krel;
            size_t sb = (size_t)(ct * 128 + row) * 1024 + e0 + krel;
            gl_lds16(&Axp[sa], &Ab[buf * 8192 + slice * 512]);
            gl_lds16(&Qp[sb],  &Qb[buf * 8192 + slice * 512]);
            gl_lds16(&Kp[sb],  &Kb[buf * 8192 + slice * 512]);
        }
    };

    stageAB(0, 0);
    #pragma unroll
    for (int i = 0; i < 2; ++i) {
        int slice = w * 2 + i;
        int row = slice * 8 + (l >> 3);
        gl_lds16(&WvT[(size_t)(ct * 128 + row) * 1024 + lc * 8], &Vb[slice * 512]);
    }
    asm volatile("s_waitcnt vmcnt(0)" ::: "memory");
    __builtin_amdgcn_s_barrier();

    for (int t = 0; t < 32; ++t) {
        __builtin_amdgcn_s_barrier();              // bar1: all done with t-1 compute
        __builtin_amdgcn_sched_barrier(0);
        if (t < 31) stageAB((t + 1) & 1, (t + 1) * 32);      // 6 loads/wave
        {   // half of v window (t>>1)+1 : 1 load/wave (t <= 29)
            int wv = (t >> 1) + 1;
            if (wv < 16) {
                int slice = w + (t & 1) * 8;
                int row = slice * 8 + (l >> 3);
                gl_lds16(&WvT[(size_t)(ct * 128 + row) * 1024 + wv * 64 + lc * 8],
                         &Vb[(wv & 1) * 8192 + slice * 512]);
            }
        }
        __builtin_amdgcn_sched_barrier(0);
        if (t < 30)       asm volatile("s_waitcnt vmcnt(7)" ::: "memory");
        else if (t == 30) asm volatile("s_waitcnt vmcnt(6)" ::: "memory");
        else              asm volatile("s_waitcnt vmcnt(0)" ::: "memory");
        __builtin_amdgcn_sched_barrier(0);
        __builtin_amdgcn_s_barrier();              // bar2: everyone's cur loads landed
        __builtin_amdgcn_sched_barrier(0);

        const unsigned short* Ac = &Ab[(t & 1) * 8192];
        const unsigned short* Qc = &Qb[(t & 1) * 8192];
        const unsigned short* Kc = &Kb[(t & 1) * 8192];
        const unsigned short* Vc = &Vb[((t >> 1) & 1) * 8192];
        const int ca = (l >> 4) ^ (l & 7);         // phys chunk of hi frag
        const int cb = ca ^ 4;                     // lo frag
        const int cv = ca ^ ((t & 1) << 2);        // v frag (window parity)

        bfrag afh[4], afl[4];
        #pragma unroll
        for (int m = 0; m < 4; ++m) {
            int row = wm * 64 + m * 16 + (l & 15);
            afh[m] = *(const bfrag*)&Ac[row * 64 + ca * 8];
            afl[m] = *(const bfrag*)&Ac[row * 64 + cb * 8];
        }
        #pragma unroll
        for (int n = 0; n < 2; ++n) {
            int nr = wn * 32 + n * 16 + (l & 15);
            bfrag bv = *(const bfrag*)&Vc[nr * 64 + cv * 8];
            #pragma unroll
            for (int m = 0; m < 4; ++m) accv[m][n] = MFMA(afh[m], bv, accv[m][n]);
        }
        #pragma unroll
        for (int n = 0; n < 2; ++n) {
            int nr = wn * 32 + n * 16 + (l & 15);
            bfrag bh = *(const bfrag*)&Qc[nr * 64 + ca * 8];
            bfrag bl = *(const bfrag*)&Qc[nr * 64 + cb * 8];
            #pragma unroll
            for (int m = 0; m < 4; ++m) {
                accq[m][n] = MFMA(afh[m], bh, accq[m][n]);
                accq[m][n] = MFMA(afh[m], bl, accq[m][n]);
                accq[m][n] = MFMA(afl[m], bh, accq[m][n]);
            }
        }
        #pragma unroll
        for (int n = 0; n < 2; ++n) {
            int nr = wn * 32 + n * 16 + (l & 15);
            bfrag bh = *(const bfrag*)&Kc[nr * 64 + ca * 8];
            bfrag bl = *(const bfrag*)&Kc[nr * 64 + cb * 8];
            #pragma unroll
            for (int m = 0; m < 4; ++m) {
                acck[m][n] = MFMA(afh[m], bh, acck[m][n]);
                acck[m][n] = MFMA(afh[m], bl, acck[m][n]);
                acck[m][n] = MFMA(afl[m], bh, acck[m][n]);
            }
        }
    }

    // epilogue
    #pragma unroll
    for (int m = 0; m < 4; ++m)
        #pragma unroll
        for (int r = 0; r < 4; ++r) {
            int row = rt * 128 + wm * 64 + m * 16 + (l >> 4) * 4 + r;
            #pragma unroll
            for (int n = 0; n < 2; ++n) {
                int col = ct * 128 + wn * 32 + n * 16 + (l & 15);
                float fq = accq[m][n][r] * QSC;
                unsigned short hb = f2bh(fq);
                qh[(size_t)row * 1024 + col] = hb;
                __hip_fp8_e4m3 e((fq - bh2f(hb)) * 256.0f);
                ql8[(size_t)row * 1024 + col] = *reinterpret_cast<unsigned char*>(&e);
                float fk = acck[m][n][r];
                unsigned short kb = f2bh(fk);
                kh[(size_t)row * 1024 + col] = kb;
                kl[(size_t)row * 1024 + col] = f2bh(fk - bh2f(kb));
            }
        }
    // v: write transposed vT[(h*2+b)*64 + d][t], pack 4 consecutive t (acc r=0..3)
    #pragma unroll
    for (int m = 0; m < 4; ++m) {
        int t0g = rt * 128 + wm * 64 + m * 16 + (l >> 4) * 4;
        int b_ = t0g >> 11, t0 = t0g & 2047;
        #pragma unroll
        for (int n = 0; n < 2; ++n) {
            int col = ct * 128 + wn * 32 + n * 16 + (l & 15);
            int h_ = col >> 6, d = col & 63;
            us4 pk;
            #pragma unroll
            for (int r = 0; r < 4; ++r) pk[r] = f2bh(accv[m][n][r]);
            *(us4*)&vT[((size_t)((h_ * 2 + b_) * 64 + d)) * 2048 + t0] = pk;
        }
    }
}

// ---------------------------------------------------------------------------
// attn helpers
// ---------------------------------------------------------------------------
__device__ __forceinline__ void stage_kv(
    const unsigned short* __restrict__ kh, const unsigned short* __restrict__ kl,
    const unsigned short* __restrict__ vT,
    unsigned short* Khb, unsigned short* Klb, unsigned short* Vtb,
    int w, int l, int b, int h, int kt)
{
    #pragma unroll
    for (int i = 0; i < 2; ++i) {
        int pbase = (w * 2 + i) * 1024;    // uniform 1KB slice base (bytes)
        int p = pbase + l * 16;
        int row = p >> 7, slot = (p >> 4) & 7;
        int chunk = slot ^ (row & 7);      // inverse-swizzled source chunk
        size_t srcK = (size_t)(b * 2048 + kt * 64 + row) * 1024 + h * 64 + chunk * 8;
        size_t srcV = ((size_t)(h * 2 + b) * 64 + row) * 2048 + (size_t)kt * 64 + chunk * 8;
        gl_lds16(&kh[srcK], &Khb[pbase >> 1]);
        gl_lds16(&kl[srcK], &Klb[pbase >> 1]);
        gl_lds16(&vT[srcV], &Vtb[pbase >> 1]);
    }
}

// One 64-key flash step: split QK^T, exp2 softmax (defer-max THR=8), P->LDS,
// PV with ones-MFMA row-sum.  Denominator accumulates in Osum (matrix pipe).
__device__ __forceinline__ void attn_step(
    const unsigned short* Khb, const unsigned short* Klb, const unsigned short* Vtb,
    unsigned short* Pl, const bfrag* qfh, const bfrag* qfl,
    facc* O, facc& Osum, float* mrow, bfrag ones, int w, int l, bool diag)
{
    facc S[4];
    #pragma unroll
    for (int f = 0; f < 4; ++f) S[f] = (facc)(0.0f);
    __builtin_amdgcn_s_setprio(1);
    #pragma unroll
    for (int s = 0; s < 2; ++s) {
        #pragma unroll
        for (int f = 0; f < 4; ++f) {
            int key = f * 16 + (l & 15);
            int ch = (s * 4 + (l >> 4)) ^ (key & 7);
            bfrag kbh = *(const bfrag*)&Khb[key * 64 + ch * 8];
            bfrag kbl = *(const bfrag*)&Klb[key * 64 + ch * 8];
            S[f] = MFMA(qfh[s], kbh, S[f]);
            S[f] = MFMA(qfh[s], kbl, S[f]);
            S[f] = MFMA(qfl[s], kbh, S[f]);
        }
    }
    __builtin_amdgcn_s_setprio(0);
    if (diag) {
        #pragma unroll
        for (int f = 0; f < 4; ++f) {
            int keyl = f * 16 + (l & 15);
            #pragma unroll
            for (int r = 0; r < 4; ++r) {
                int qls = w * 16 + (l >> 4) * 4 + r;
                if (keyl > qls) S[f][r] = -1e30f;
            }
        }
    }
    // row max (16-lane groups) + deferred rescale
    float mx[4];
    float dmax = -3.0e38f;
    #pragma unroll
    for (int r = 0; r < 4; ++r) {
        float m0 = fmaxf(fmaxf(S[0][r], S[1][r]), fmaxf(S[2][r], S[3][r]));
        m0 = fmaxf(m0, __shfl_xor(m0, 1));
        m0 = fmaxf(m0, __shfl_xor(m0, 2));
        m0 = fmaxf(m0, __shfl_xor(m0, 4));
        m0 = fmaxf(m0, __shfl_xor(m0, 8));
        mx[r] = m0;
        dmax = fmaxf(dmax, m0 - mrow[r]);
    }
    if (!__all(dmax <= 8.0f)) {            // wave-uniform, rare after warmup
        #pragma unroll
        for (int r = 0; r < 4; ++r) {
            float mn = fmaxf(mrow[r], mx[r]);
            float fac = EXP2(mrow[r] - mn);
            mrow[r] = mn;
            O[0][r] *= fac; O[1][r] *= fac; O[2][r] *= fac; O[3][r] *= fac;
            Osum[r] *= fac;
        }
    }
    #pragma unroll
    for (int r = 0; r < 4; ++r)
        #pragma unroll
        for (int f = 0; f < 4; ++f) S[f][r] = EXP2(S[f][r] - mrow[r]);
    // P -> LDS (bf16, swizzled rows); same-wave rows only, lgkmcnt orders it.
    #pragma unroll
    for (int f = 0; f < 4; ++f) {
        int key = f * 16 + (l & 15);
        #pragma unroll
        for (int r = 0; r < 4; ++r) {
            int qr = w * 16 + (l >> 4) * 4 + r;
            Pl[qr * 64 + (((key >> 3) ^ (qr & 7)) * 8) + (key & 7)] = f2bh(S[f][r]);
        }
    }
    // PV + denominator via ones-MFMA
    __builtin_amdgcn_s_setprio(1);
    #pragma unroll
    for (int s = 0; s < 2; ++s) {
        int qa = w * 16 + (l & 15);
        int cha = (s * 4 + (l >> 4)) ^ (qa & 7);
        bfrag pa = *(const bfrag*)&Pl[qa * 64 + cha * 8];
        Osum = MFMA(pa, ones, Osum);
        #pragma unroll
        for (int f = 0; f < 4; ++f) {
            int d = f * 16 + (l & 15);
            int chv = (s * 4 + (l >> 4)) ^ (d & 7);
            bfrag vb = *(const bfrag*)&Vtb[d * 64 + chv * 8];
            O[f] = MFMA(pa, vb, O[f]);
        }
    }
    __builtin_amdgcn_s_setprio(0);
}

// ---------------------------------------------------------------------------
// attn_mfma: paired-q-tile flash attention (R6 structure).  grid (16, 32),
// block 256 (4 waves), 56KB static LDS, 2 blocks/CU.  K/V double-buffered;
// prefetch issued before a raw s_barrier (stays in flight), drained by the
// next __syncthreads.
// ---------------------------------------------------------------------------
__global__ __launch_bounds__(256, 2) void attn_mfma(
    const unsigned short* __restrict__ qh, const unsigned char* __restrict__ ql8,
    const unsigned short* __restrict__ kh, const unsigned short* __restrict__ kl,
    const unsigned short* __restrict__ vT, unsigned short* __restrict__ att)
{
    __shared__ unsigned short Kh[2][4096], Kl[2][4096], Vt[2][4096], Pl[4096];
    const int tid = threadIdx.x, w = tid >> 6, l = tid & 63;
    const int dd = blockIdx.y * 16 + blockIdx.x;
    const int xcd = dd & 7, sl = dd >> 3;
    const int hb = xcd * 4 + (sl >> 4);
    const int bx = sl & 15;
    const int qtA = 31 - bx, qtB = bx;     // qtA >= 16 > qtB always
    const int h = hb >> 1, b = hb & 1;

    bfrag ones;
    #pragma unroll
    for (int j = 0; j < 8; ++j) ones[j] = (short)0x3F80;   // bf16 1.0

    bfrag qfhA[2], qflA[2], qfhB[2], qflB[2];
    {
        const int qrowA = qtA * 64 + w * 16 + (l & 15);
        const size_t qoffA = (size_t)(b * 2048 + qrowA) * 1024 + h * 64 + (l >> 4) * 8;
        qfhA[0] = *(const bfrag*)&qh[qoffA];
        qfhA[1] = *(const bfrag*)&qh[qoffA + 32];
        qflA[0] = f8frag(*(const uint2*)&ql8[qoffA]);
        qflA[1] = f8frag(*(const uint2*)&ql8[qoffA + 32]);
        const int qrowB = qtB * 64 + w * 16 + (l & 15);
        const size_t qoffB = (size_t)(b * 2048 + qrowB) * 1024 + h * 64 + (l >> 4) * 8;
        qfhB[0] = *(const bfrag*)&qh[qoffB];
        qfhB[1] = *(const bfrag*)&qh[qoffB + 32];
        qflB[0] = f8frag(*(const uint2*)&ql8[qoffB]);
        qflB[1] = f8frag(*(const uint2*)&ql8[qoffB + 32]);
    }

    facc OA[4], OB[4], OsA, OsB;
    float mA[4], mB[4];
    #pragma unroll
    for (int f = 0; f < 4; ++f) { OA[f] = (facc)(0.0f); OB[f] = (facc)(0.0f); }
    OsA = (facc)(0.0f); OsB = (facc)(0.0f);
    #pragma unroll
    for (int r = 0; r < 4; ++r) { mA[r] = -1e30f; mB[r] = -1e30f; }

    stage_kv(kh, kl, vT, Kh[0], Kl[0], Vt[0], w, l, b, h, 0);
    for (int kt = 0; kt <= qtA; ++kt) {
        const int cur = kt & 1;
        __syncthreads();                   // drains my prior stage; WAR-protects buf
        if (kt < qtA)
            stage_kv(kh, kl, vT, Kh[cur ^ 1], Kl[cur ^ 1], Vt[cur ^ 1], w, l, b, h, kt + 1);
        __builtin_amdgcn_sched_barrier(0);
        __builtin_amdgcn_s_barrier();      // raw: prefetch stays in flight
        __builtin_amdgcn_sched_barrier(0);
        attn_step(Kh[cur], Kl[cur], Vt[cur], Pl, qfhA, qflA, OA, OsA, mA, ones,
                  w, l, kt == qtA);
        if (kt <= qtB)
            attn_step(Kh[cur], Kl[cur], Vt[cur], Pl, qfhB, qflB, OB, OsB, mB, ones,
                      w, l, kt == qtB);
    }

    #pragma unroll
    for (int f = 0; f < 4; ++f) {
        int d = h * 64 + f * 16 + (l & 15);
        #pragma unroll
        for (int r = 0; r < 4; ++r) {
            int tA = qtA * 64 + w * 16 + (l >> 4) * 4 + r;
            att[(size_t)(b * 2048 + tA) * 1024 + d] = f2bh(OA[f][r] / OsA[r]);
            int tB = qtB * 64 + w * 16 + (l >> 4) * 4 + r;
            att[(size_t)(b * 2048 + tB) * 1024 + d] = f2bh(OB[f][r] / OsB[r]);
        }
    }
}

// ---------------------------------------------------------------------------
// outproj: out[4096,1024] = att @ Wo^T.  BK=64 swizzled, double-buffered with
// the prefetch-across-raw-barrier loop.  grid (32, 8), 64KB LDS.
// ---------------------------------------------------------------------------
__global__ __launch_bounds__(256, 2) void outproj(
    const unsigned short* __restrict__ att, const unsigned short* __restrict__ WoB,
    float* __restrict__ out)
{
    __shared__ unsigned short Ab[2][128 * 64], Bb[2][128 * 64];
    const int tid = threadIdx.x, w = tid >> 6, l = tid & 63;
    const int wm = w >> 1, wn = w & 1;
    const int rt = blockIdx.x, ct = blockIdx.y;

    const int lc = (l & 7) ^ (l >> 3);         // logical chunk (0..7) -> k-offset lc*8
    facc acc[4][4];
    #pragma unroll
    for (int i = 0; i < 4; ++i)
        #pragma unroll
        for (int j = 0; j < 4; ++j) acc[i][j] = (facc)(0.0f);

    auto stage = [&](int buf, int e0) {
        #pragma unroll
        for (int i = 0; i < 4; ++i) {
            int slice = w * 4 + i;
            int row = slice * 8 + (l >> 3);
            gl_lds16(&att[(size_t)(rt * 128 + row) * 1024 + e0 + lc * 8], &Ab[buf][slice * 512]);
            gl_lds16(&WoB[(size_t)(ct * 128 + row) * 1024 + e0 + lc * 8], &Bb[buf][slice * 512]);
        }
    };

    stage(0, 0);
    int cur = 0;
    for (int t = 0; t < 16; ++t) {
        __syncthreads();
        if (t < 15) stage(cur ^ 1, (t + 1) * 64);
        __builtin_amdgcn_sched_barrier(0);
        __builtin_amdgcn_s_barrier();
        __builtin_amdgcn_sched_barrier(0);
        #pragma unroll
        for (int s = 0; s < 2; ++s) {
            const int slot = (s * 4 + (l >> 4)) ^ (l & 7);
            bfrag af[4], bf_[4];
            #pragma unroll
            for (int m = 0; m < 4; ++m)
                af[m] = *(const bfrag*)&Ab[cur][(wm * 64 + m * 16 + (l & 15)) * 64 + slot * 8];
            #pragma unroll
            for (int n = 0; n < 4; ++n)
                bf_[n] = *(const bfrag*)&Bb[cur][(wn * 64 + n * 16 + (l & 15)) * 64 + slot * 8];
            #pragma unroll
            for (int m = 0; m < 4; ++m)
                #pragma unroll
                for (int n = 0; n < 4; ++n)
                    acc[m][n] = MFMA(af[m], bf_[n], acc[m][n]);
        }
        cur ^= 1;
    }
    #pragma unroll
    for (int m = 0; m < 4; ++m)
        #pragma unroll
        for (int r = 0; r < 4; ++r) {
            int row = rt * 128 + wm * 64 + m * 16 + (l >> 4) * 4 + r;
            #pragma unroll
            for (int n = 0; n < 4; ++n) {
                int col = ct * 128 + wn * 64 + n * 16 + (l & 15);
                out[(size_t)row * 1024 + col] = acc[m][n][r];
            }
        }
}

// ---------------------------------------------------------------------------
extern "C" void kernel_launch(void* const* d_in, const int* in_sizes, int n_in,
                              void* d_out, int out_size, void* d_ws, size_t ws_size,
                              hipStream_t stream) {
    const float* x  = (const float*)d_in[0];
    // d_in[1]: causal mask (applied analytically)
    const float* Wq = (const float*)d_in[2];
    const float* Wk = (const float*)d_in[3];
    const float* Wv = (const float*)d_in[4];
    const float* Wo = (const float*)d_in[5];

    uint8_t* wsb = (uint8_t*)d_ws;
    const size_t MB = 1024 * 1024;
    // 64MB layout.  xh overlays att (xh dead before attn writes att).
    unsigned short* WqTh = (unsigned short*)(wsb + 0 * MB);
    unsigned short* WqTl = (unsigned short*)(wsb + 2 * MB);
    unsigned short* WkTh = (unsigned short*)(wsb + 4 * MB);
    unsigned short* WkTl = (unsigned short*)(wsb + 6 * MB);
    unsigned short* WvT  = (unsigned short*)(wsb + 8 * MB);
    unsigned short* qh   = (unsigned short*)(wsb + 10 * MB);  // 8MB
    unsigned char*  ql8  = (unsigned char*)(wsb + 18 * MB);   // 4MB fp8
    unsigned short* kh   = (unsigned short*)(wsb + 22 * MB);  // 8MB
    unsigned short* kl   = (unsigned short*)(wsb + 30 * MB);  // 8MB
    unsigned short* vT   = (unsigned short*)(wsb + 38 * MB);  // 8MB
    unsigned short* att  = (unsigned short*)(wsb + 46 * MB);  // 8MB
    unsigned short* xh   = (unsigned short*)(wsb + 46 * MB);  // 8MB (alias att)
    unsigned short* WoB  = (unsigned short*)(wsb + 54 * MB);  // 2MB
    unsigned short* xl   = (unsigned short*)(wsb + 56 * MB);  // 8MB

    hipFuncSetAttribute((const void*)qkv_fused,
                        hipFuncAttributeMaxDynamicSharedMemorySize, 131072);

    prep_xw<<<dim3(5120), 256, 0, stream>>>(x, Wo, xh, xl, WoB);
    prep_w<<<dim3(16, 16, 3), 256, 0, stream>>>(Wq, Wk, Wv, WqTh, WqTl, WkTh, WkTl, WvT);
    qkv_fused<<<dim3(8, 32), 512, 131072, stream>>>(xh, xl, WqTh, WqTl, WkTh, WkTl, WvT,
                                                    qh, ql8, kh, kl, vT);
    attn_mfma<<<dim3(16, 32), 256, 0, stream>>>(qh, ql8, kh, kl, vT, att);
    outproj<<<dim3(32, 8), 256, 0, stream>>>(att, WoB, (float*)d_out);
}

// Round 11
// 164.549 us; speedup vs baseline: 2.3995x; 1.0202x over previous
//
#include <hip/hip_runtime.h>
#include <hip/hip_fp8.h>
#include <stdint.h>

// (B,T,E,H,D) = (2,2048,1024,16,64)
constexpr float INV_SCALE = 0.022097086912079608f;  // 1/sqrt(2048)
constexpr float LOG2E = 1.4426950408889634f;
constexpr float QSC = INV_SCALE * LOG2E;            // q pre-scale: softmax in exp2 domain

typedef __attribute__((ext_vector_type(8))) short bfrag;          // 8 bf16 (4 VGPR) MFMA frag
typedef __attribute__((ext_vector_type(4))) float facc;           // 4 f32 MFMA acc
typedef __attribute__((ext_vector_type(4))) unsigned short us4;   // 4 bf16 = 8B

#define MFMA(a, b, c) __builtin_amdgcn_mfma_f32_16x16x32_bf16((a), (b), (c), 0, 0, 0)
#define EXP2(x) __builtin_amdgcn_exp2f(x)

__device__ __forceinline__ unsigned short f2bh(float f) {        // f32 -> bf16 RNE
    union { float f; unsigned int u; } cv; cv.f = f;
    unsigned int u = cv.u;
    u += 0x7FFFu + ((u >> 16) & 1u);
    return (unsigned short)(u >> 16);
}
__device__ __forceinline__ float bh2f(unsigned short h) {
    union { unsigned int u; float f; } cv; cv.u = ((unsigned int)h) << 16;
    return cv.f;
}
__device__ __forceinline__ void gl_lds16(const unsigned short* g, unsigned short* lds) {
    // async 16B/lane global->LDS; dst is wave-uniform base, lane i lands at dst+16*i
    __builtin_amdgcn_global_load_lds(
        (const __attribute__((address_space(1))) unsigned int*)g,
        (__attribute__((address_space(3))) unsigned int*)lds, 16, 0, 0);
}
// 8 fp8(e4m3, x256) bytes -> bf16 frag (undo the 256x scale)
__device__ __forceinline__ bfrag f8frag(uint2 raw) {
    union { uint2 u; unsigned char b[8]; } cv; cv.u = raw;
    bfrag r;
    #pragma unroll
    for (int j = 0; j < 8; ++j) {
        const __hip_fp8_e4m3* t = reinterpret_cast<const __hip_fp8_e4m3*>(&cv.b[j]);
        r[j] = (short)f2bh((float)(*t) * 0.00390625f);
    }
    return r;
}
// one DPP max-reduce stage over the 16-lane row (pure VALU, no LDS)
template<int CTRL>
__device__ __forceinline__ float dppmax(float v) {
    int s = __builtin_amdgcn_update_dpp(0, __builtin_bit_cast(int, v), CTRL, 0xF, 0xF, true);
    return fmaxf(v, __builtin_bit_cast(float, s));
}
__device__ __forceinline__ float rowmax16(float v) {
    v = dppmax<0xB1>(v);    // quad_perm [1,0,3,2]  (xor 1)
    v = dppmax<0x4E>(v);    // quad_perm [2,3,0,1]  (xor 2)
    v = dppmax<0x141>(v);   // row_half_mirror      (covers xor 4)
    v = dppmax<0x140>(v);   // row_mirror           (covers xor 8)
    return v;
}

// ---------------------------------------------------------------------------
// prep_xw: fused  Wo fp32->bf16 (blocks 0..1023)  +  x fp32->hi/lo split
// (blocks 1024..5119).
// ---------------------------------------------------------------------------
__global__ __launch_bounds__(256) void prep_xw(const float* __restrict__ x,
                                               const float* __restrict__ Wo,
                                               unsigned short* __restrict__ xh,
                                               unsigned short* __restrict__ xl,
                                               unsigned short* __restrict__ WoB) {
    if (blockIdx.x < 1024) {
        int idx = blockIdx.x * 256 + threadIdx.x;   // f4 index, 262144 total
        facc v = *(const facc*)&Wo[(size_t)idx * 4];
        us4 o;
        #pragma unroll
        for (int j = 0; j < 4; ++j) o[j] = f2bh(v[j]);
        *(us4*)&WoB[(size_t)idx * 4] = o;
    } else {
        int idx = (blockIdx.x - 1024) * 256 + threadIdx.x;  // f4 idx, 1,048,576 total
        facc v = *(const facc*)&x[(size_t)idx * 4];
        us4 hv, lv;
        #pragma unroll
        for (int j = 0; j < 4; ++j) {
            unsigned short hb = f2bh(v[j]);
            hv[j] = hb;
            lv[j] = f2bh(v[j] - bh2f(hb));
        }
        *(us4*)&xh[(size_t)idx * 4] = hv;
        *(us4*)&xl[(size_t)idx * 4] = lv;
    }
}

// ---------------------------------------------------------------------------
// prep_w: per head, transpose W[h][1024 e][64 i] -> WT[h*64+i][1024 e] with
// hi/lo bf16 split for Wq/Wk, hi-only for Wv.  grid (16,16,3), block 256.
// ---------------------------------------------------------------------------
__global__ __launch_bounds__(256) void prep_w(
    const float* __restrict__ Wq, const float* __restrict__ Wk, const float* __restrict__ Wv,
    unsigned short* __restrict__ WqTh, unsigned short* __restrict__ WqTl,
    unsigned short* __restrict__ WkTh, unsigned short* __restrict__ WkTl,
    unsigned short* __restrict__ WvT)
{
    __shared__ float tile[64][65];
    const int tid = threadIdx.x;
    const int et = blockIdx.x, h = blockIdx.y, m = blockIdx.z;
    const float* W = (m == 0) ? Wq : (m == 1) ? Wk : Wv;
    #pragma unroll
    for (int rep = 0; rep < 4; ++rep) {
        int idx = rep * 256 + tid;            // f4 idx over [64e][16 i4]
        int e = idx >> 4, i4 = (idx & 15) * 4;
        facc v = *(const facc*)&W[(size_t)h * 65536 + (size_t)(et * 64 + e) * 64 + i4];
        tile[e][i4] = v.x; tile[e][i4 + 1] = v.y; tile[e][i4 + 2] = v.z; tile[e][i4 + 3] = v.w;
    }
    __syncthreads();
    unsigned short* Oh = (m == 0) ? WqTh : (m == 1) ? WkTh : WvT;
    unsigned short* Ol = (m == 0) ? WqTl : WkTl;   // unused when m==2
    #pragma unroll
    for (int rep = 0; rep < 4; ++rep) {
        int idx = rep * 256 + tid;            // [64 i][16 e4]
        int i = idx >> 4, e4 = (idx & 15) * 4;
        us4 hv, lv;
        #pragma unroll
        for (int j = 0; j < 4; ++j) {
            float f = tile[e4 + j][i];
            unsigned short hb = f2bh(f);
            hv[j] = hb;
            lv[j] = f2bh(f - bh2f(hb));
        }
        size_t o = (size_t)(h * 64 + i) * 1024 + et * 64 + e4;
        *(us4*)&Oh[o] = hv;
        if (m < 2) *(us4*)&Ol[o] = lv;
    }
}

// ---------------------------------------------------------------------------
// qkv_fused: block (ct, rt) computes q,k,v for rows [rt*128,+128), cols
// [ct*64,+64) in one K=1024 pass.  256 threads (4 waves, 2x2); per wave
// 64 rows x 32 cols per target.  72KB dynamic LDS -> 2 blocks/CU = two
// INDEPENDENT barrier domains per CU (stall overlap).  Counted-vmcnt
// pipeline (vmcnt(9)).  grid (16 ct, 32 rt) = 512 blocks = 2/CU exact;
// same-ct blocks share an XCD (weights L2-resident).
// ---------------------------------------------------------------------------
__global__ __launch_bounds__(256, 2) void qkv_fused(
    const unsigned short* __restrict__ xh, const unsigned short* __restrict__ xl,
    const unsigned short* __restrict__ WqTh, const unsigned short* __restrict__ WqTl,
    const unsigned short* __restrict__ WkTh, const unsigned short* __restrict__ WkTl,
    const unsigned short* __restrict__ WvT,
    unsigned short* __restrict__ qh, unsigned char* __restrict__ ql8,
    unsigned short* __restrict__ kh, unsigned short* __restrict__ kl,
    unsigned short* __restrict__ vT)
{
    extern __shared__ unsigned short sm[];
    unsigned short* Ab = sm;               // [2][128*64] 32KB (x hi|lo, XOR-8 swz)
    unsigned short* Qb = sm + 16384;       // [2][64*64] 16KB
    unsigned short* Kb = sm + 24576;       // [2][64*64] 16KB
    unsigned short* Vb = sm + 32768;       // [2][64*32] 8KB  ((row>>1)&3 swz)
    const int tid = threadIdx.x;
    const int w = tid >> 6, l = tid & 63;
    const int wm = w >> 1, wn = w & 1;     // 2 x 2 wave grid
    const int ct = blockIdx.x, rt = blockIdx.y;

    const int lc = (l & 7) ^ (l >> 3);     // logical chunk at dest (128B rows)
    const int krel = (lc & 3) * 8;
    const unsigned short* Axp = (lc < 4) ? xh : xl;
    const unsigned short* Qp  = (lc < 4) ? WqTh : WqTl;
    const unsigned short* Kp  = (lc < 4) ? WkTh : WkTl;
    const int lcv = (l & 3) ^ ((l >> 3) & 3);   // V logical chunk (64B rows)

    facc accq[4][2], acck[4][2], accv[4][2];
    #pragma unroll
    for (int m = 0; m < 4; ++m)
        #pragma unroll
        for (int n = 0; n < 2; ++n) {
            accq[m][n] = (facc)(0.0f); acck[m][n] = (facc)(0.0f); accv[m][n] = (facc)(0.0f);
        }

    auto stage = [&](int buf, int e0) {
        // A: 16KB/buf, 4 slices/wave
        #pragma unroll
        for (int i = 0; i < 4; ++i) {
            int slice = w * 4 + i;                    // 0..15
            int row = slice * 8 + (l >> 3);
            gl_lds16(&Axp[(size_t)(rt * 128 + row) * 1024 + e0 + krel],
                     &Ab[buf * 8192 + slice * 512]);
        }
        // Q,K: 8KB/buf, 2 slices/wave each
        #pragma unroll
        for (int i = 0; i < 2; ++i) {
            int slice = w * 2 + i;                    // 0..7
            int row = slice * 8 + (l >> 3);
            size_t sb = (size_t)(ct * 64 + row) * 1024 + e0 + krel;
            gl_lds16(&Qp[sb], &Qb[buf * 4096 + slice * 512]);
            gl_lds16(&Kp[sb], &Kb[buf * 4096 + slice * 512]);
        }
        // V: 4KB/buf, 1 slice/wave (64B rows, (row>>1)&3 chunk swizzle)
        {
            int row = w * 16 + (l >> 2);
            gl_lds16(&WvT[(size_t)(ct * 64 + row) * 1024 + e0 + lcv * 8],
                     &Vb[w * 1024 + (l & 63) * 0 + w * 0 + (w * 1024) * 0 + w * 1024 - w * 1024 + w * 1024 + 0]);
        }
    };
    // (note: V dest is just the wave's 1KB slice)
    auto stageV_fix = [&](int buf, int e0) {
        int row = w * 16 + (l >> 2);
        gl_lds16(&WvT[(size_t)(ct * 64 + row) * 1024 + e0 + lcv * 8],
                 &Vb[buf * 2048 + w * 512]);
    };

    // prologue: step 0 (A/Q/K via stage's first two sections + V)
    {
        #pragma unroll
        for (int i = 0; i < 4; ++i) {
            int slice = w * 4 + i;
            int row = slice * 8 + (l >> 3);
            gl_lds16(&Axp[(size_t)(rt * 128 + row) * 1024 + krel], &Ab[slice * 512]);
        }
        #pragma unroll
        for (int i = 0; i < 2; ++i) {
            int slice = w * 2 + i;
            int row = slice * 8 + (l >> 3);
            size_t sb = (size_t)(ct * 64 + row) * 1024 + krel;
            gl_lds16(&Qp[sb], &Qb[slice * 512]);
            gl_lds16(&Kp[sb], &Kb[slice * 512]);
        }
        stageV_fix(0, 0);
    }
    asm volatile("s_waitcnt vmcnt(0)" ::: "memory");
    __builtin_amdgcn_s_barrier();

    for (int t = 0; t < 32; ++t) {
        __builtin_amdgcn_s_barrier();              // bar1: all done with t-1 compute
        __builtin_amdgcn_sched_barrier(0);
        if (t < 31) {
            int buf = (t + 1) & 1, e0 = (t + 1) * 32;
            #pragma unroll
            for (int i = 0; i < 4; ++i) {
                int slice = w * 4 + i;
                int row = slice * 8 + (l >> 3);
                gl_lds16(&Axp[(size_t)(rt * 128 + row) * 1024 + e0 + krel],
                         &Ab[buf * 8192 + slice * 512]);
            }
            #pragma unroll
            for (int i = 0; i < 2; ++i) {
                int slice = w * 2 + i;
                int row = slice * 8 + (l >> 3);
                size_t sb = (size_t)(ct * 64 + row) * 1024 + e0 + krel;
                gl_lds16(&Qp[sb], &Qb[buf * 4096 + slice * 512]);
                gl_lds16(&Kp[sb], &Kb[buf * 4096 + slice * 512]);
            }
            stageV_fix(buf, e0);
        }
        __builtin_amdgcn_sched_barrier(0);
        if (t < 31) asm volatile("s_waitcnt vmcnt(9)" ::: "memory");
        else        asm volatile("s_waitcnt vmcnt(0)" ::: "memory");
        __builtin_amdgcn_sched_barrier(0);
        __builtin_amdgcn_s_barrier();              // bar2: everyone's cur loads landed
        __builtin_amdgcn_sched_barrier(0);

        const unsigned short* Ac = &Ab[(t & 1) * 8192];
        const unsigned short* Qc = &Qb[(t & 1) * 4096];
        const unsigned short* Kc = &Kb[(t & 1) * 4096];
        const unsigned short* Vc = &Vb[(t & 1) * 2048];
        const int ca = (l >> 4) ^ (l & 7);         // phys chunk of hi frag (128B rows)
        const int cb = ca ^ 4;                     // lo frag

        bfrag afh[4], afl[4];
        #pragma unroll
        for (int m = 0; m < 4; ++m) {
            int row = wm * 64 + m * 16 + (l & 15);
            afh[m] = *(const bfrag*)&Ac[row * 64 + ca * 8];
            afl[m] = *(const bfrag*)&Ac[row * 64 + cb * 8];
        }
        #pragma unroll
        for (int n = 0; n < 2; ++n) {
            int nr = wn * 32 + n * 16 + (l & 15);
            int cv = (l >> 4) ^ ((nr >> 1) & 3);   // V phys chunk (64B rows)
            bfrag bv = *(const bfrag*)&Vc[nr * 32 + cv * 8];
            #pragma unroll
            for (int m = 0; m < 4; ++m) accv[m][n] = MFMA(afh[m], bv, accv[m][n]);
        }
        #pragma unroll
        for (int n = 0; n < 2; ++n) {
            int nr = wn * 32 + n * 16 + (l & 15);
            bfrag bh = *(const bfrag*)&Qc[nr * 64 + ca * 8];
            bfrag bl = *(const bfrag*)&Qc[nr * 64 + cb * 8];
            #pragma unroll
            for (int m = 0; m < 4; ++m) {
                accq[m][n] = MFMA(afh[m], bh, accq[m][n]);
                accq[m][n] = MFMA(afh[m], bl, accq[m][n]);
                accq[m][n] = MFMA(afl[m], bh, accq[m][n]);
            }
        }
        #pragma unroll
        for (int n = 0; n < 2; ++n) {
            int nr = wn * 32 + n * 16 + (l & 15);
            bfrag bh = *(const bfrag*)&Kc[nr * 64 + ca * 8];
            bfrag bl = *(const bfrag*)&Kc[nr * 64 + cb * 8];
            #pragma unroll
            for (int m = 0; m < 4; ++m) {
                acck[m][n] = MFMA(afh[m], bh, acck[m][n]);
                acck[m][n] = MFMA(afh[m], bl, acck[m][n]);
                acck[m][n] = MFMA(afl[m], bh, acck[m][n]);
            }
        }
    }

    // epilogue
    #pragma unroll
    for (int m = 0; m < 4; ++m)
        #pragma unroll
        for (int r = 0; r < 4; ++r) {
            int row = rt * 128 + wm * 64 + m * 16 + (l >> 4) * 4 + r;
            #pragma unroll
            for (int n = 0; n < 2; ++n) {
                int col = ct * 64 + wn * 32 + n * 16 + (l & 15);
                float fq = accq[m][n][r] * QSC;
                unsigned short hb = f2bh(fq);
                qh[(size_t)row * 1024 + col] = hb;
                __hip_fp8_e4m3 e((fq - bh2f(hb)) * 256.0f);
                ql8[(size_t)row * 1024 + col] = *reinterpret_cast<unsigned char*>(&e);
                float fk = acck[m][n][r];
                unsigned short kb = f2bh(fk);
                kh[(size_t)row * 1024 + col] = kb;
                kl[(size_t)row * 1024 + col] = f2bh(fk - bh2f(kb));
            }
        }
    // v: write transposed vT[(h*2+b)*64 + d][t], pack 4 consecutive t
    #pragma unroll
    for (int m = 0; m < 4; ++m) {
        int t0g = rt * 128 + wm * 64 + m * 16 + (l >> 4) * 4;
        int b_ = t0g >> 11, t0 = t0g & 2047;
        #pragma unroll
        for (int n = 0; n < 2; ++n) {
            int col = ct * 64 + wn * 32 + n * 16 + (l & 15);
            int h_ = col >> 6, d = col & 63;
            us4 pk;
            #pragma unroll
            for (int r = 0; r < 4; ++r) pk[r] = f2bh(accv[m][n][r]);
            *(us4*)&vT[((size_t)((h_ * 2 + b_) * 64 + d)) * 2048 + t0] = pk;
        }
    }
}

// ---------------------------------------------------------------------------
// attn helpers
// ---------------------------------------------------------------------------
__device__ __forceinline__ void stage_kv(
    const unsigned short* __restrict__ kh, const unsigned short* __restrict__ kl,
    const unsigned short* __restrict__ vT,
    unsigned short* Khb, unsigned short* Klb, unsigned short* Vtb,
    int w, int l, int b, int h, int kt)
{
    #pragma unroll
    for (int i = 0; i < 2; ++i) {
        int pbase = (w * 2 + i) * 1024;    // uniform 1KB slice base (bytes)
        int p = pbase + l * 16;
        int row = p >> 7, slot = (p >> 4) & 7;
        int chunk = slot ^ (row & 7);      // inverse-swizzled source chunk
        size_t srcK = (size_t)(b * 2048 + kt * 64 + row) * 1024 + h * 64 + chunk * 8;
        size_t srcV = ((size_t)(h * 2 + b) * 64 + row) * 2048 + (size_t)kt * 64 + chunk * 8;
        gl_lds16(&kh[srcK], &Khb[pbase >> 1]);
        gl_lds16(&kl[srcK], &Klb[pbase >> 1]);
        gl_lds16(&vT[srcV], &Vtb[pbase >> 1]);
    }
}

// One 64-key flash step: split QK^T, exp2 softmax (defer-max THR=8, DPP
// max-reduce), P->LDS, PV with ones-MFMA row-sum.
__device__ __forceinline__ void attn_step(
    const unsigned short* Khb, const unsigned short* Klb, const unsigned short* Vtb,
    unsigned short* Pl, const bfrag* qfh, const bfrag* qfl,
    facc* O, facc& Osum, float* mrow, bfrag ones, int w, int l, bool diag)
{
    facc S[4];
    #pragma unroll
    for (int f = 0; f < 4; ++f) S[f] = (facc)(0.0f);
    __builtin_amdgcn_s_setprio(1);
    #pragma unroll
    for (int s = 0; s < 2; ++s) {
        #pragma unroll
        for (int f = 0; f < 4; ++f) {
            int key = f * 16 + (l & 15);
            int ch = (s * 4 + (l >> 4)) ^ (key & 7);
            bfrag kbh = *(const bfrag*)&Khb[key * 64 + ch * 8];
            bfrag kbl = *(const bfrag*)&Klb[key * 64 + ch * 8];
            S[f] = MFMA(qfh[s], kbh, S[f]);
            S[f] = MFMA(qfh[s], kbl, S[f]);
            S[f] = MFMA(qfl[s], kbh, S[f]);
        }
    }
    __builtin_amdgcn_s_setprio(0);
    if (diag) {
        #pragma unroll
        for (int f = 0; f < 4; ++f) {
            int keyl = f * 16 + (l & 15);
            #pragma unroll
            for (int r = 0; r < 4; ++r) {
                int qls = w * 16 + (l >> 4) * 4 + r;
                if (keyl > qls) S[f][r] = -1e30f;
            }
        }
    }
    // row max via DPP (VALU-only) + deferred rescale
    float mx[4];
    float dmax = -3.0e38f;
    #pragma unroll
    for (int r = 0; r < 4; ++r) {
        float m0 = fmaxf(fmaxf(S[0][r], S[1][r]), fmaxf(S[2][r], S[3][r]));
        m0 = rowmax16(m0);
        mx[r] = m0;
        dmax = fmaxf(dmax, m0 - mrow[r]);
    }
    if (!__all(dmax <= 8.0f)) {            // wave-uniform, rare after warmup
        #pragma unroll
        for (int r = 0; r < 4; ++r) {
            float mn = fmaxf(mrow[r], mx[r]);
            float fac = EXP2(mrow[r] - mn);
            mrow[r] = mn;
            O[0][r] *= fac; O[1][r] *= fac; O[2][r] *= fac; O[3][r] *= fac;
            Osum[r] *= fac;
        }
    }
    #pragma unroll
    for (int r = 0; r < 4; ++r)
        #pragma unroll
        for (int f = 0; f < 4; ++f) S[f][r] = EXP2(S[f][r] - mrow[r]);
    // P -> LDS (bf16, swizzled rows); same-wave rows only, lgkmcnt orders it.
    #pragma unroll
    for (int f = 0; f < 4; ++f) {
        int key = f * 16 + (l & 15);
        #pragma unroll
        for (int r = 0; r < 4; ++r) {
            int qr = w * 16 + (l >> 4) * 4 + r;
            Pl[qr * 64 + (((key >> 3) ^ (qr & 7)) * 8) + (key & 7)] = f2bh(S[f][r]);
        }
    }
    // PV + denominator via ones-MFMA
    __builtin_amdgcn_s_setprio(1);
    #pragma unroll
    for (int s = 0; s < 2; ++s) {
        int qa = w * 16 + (l & 15);
        int cha = (s * 4 + (l >> 4)) ^ (qa & 7);
        bfrag pa = *(const bfrag*)&Pl[qa * 64 + cha * 8];
        Osum = MFMA(pa, ones, Osum);
        #pragma unroll
        for (int f = 0; f < 4; ++f) {
            int d = f * 16 + (l & 15);
            int chv = (s * 4 + (l >> 4)) ^ (d & 7);
            bfrag vb = *(const bfrag*)&Vtb[d * 64 + chv * 8];
            O[f] = MFMA(pa, vb, O[f]);
        }
    }
    __builtin_amdgcn_s_setprio(0);
}

// ---------------------------------------------------------------------------
// attn_mfma: paired-q-tile flash attention.  grid (16, 32), block 256
// (4 waves), 56KB static LDS, 2 blocks/CU.  K/V double-buffered; prefetch
// issued before a raw s_barrier (stays in flight), drained by next sync.
// ---------------------------------------------------------------------------
__global__ __launch_bounds__(256, 2) void attn_mfma(
    const unsigned short* __restrict__ qh, const unsigned char* __restrict__ ql8,
    const unsigned short* __restrict__ kh, const unsigned short* __restrict__ kl,
    const unsigned short* __restrict__ vT, unsigned short* __restrict__ att)
{
    __shared__ unsigned short Kh[2][4096], Kl[2][4096], Vt[2][4096], Pl[4096];
    const int tid = threadIdx.x, w = tid >> 6, l = tid & 63;
    const int dd = blockIdx.y * 16 + blockIdx.x;
    const int xcd = dd & 7, sl = dd >> 3;
    const int hb = xcd * 4 + (sl >> 4);
    const int bx = sl & 15;
    const int qtA = 31 - bx, qtB = bx;     // qtA >= 16 > qtB always
    const int h = hb >> 1, b = hb & 1;

    bfrag ones;
    #pragma unroll
    for (int j = 0; j < 8; ++j) ones[j] = (short)0x3F80;   // bf16 1.0

    bfrag qfhA[2], qflA[2], qfhB[2], qflB[2];
    {
        const int qrowA = qtA * 64 + w * 16 + (l & 15);
        const size_t qoffA = (size_t)(b * 2048 + qrowA) * 1024 + h * 64 + (l >> 4) * 8;
        qfhA[0] = *(const bfrag*)&qh[qoffA];
        qfhA[1] = *(const bfrag*)&qh[qoffA + 32];
        qflA[0] = f8frag(*(const uint2*)&ql8[qoffA]);
        qflA[1] = f8frag(*(const uint2*)&ql8[qoffA + 32]);
        const int qrowB = qtB * 64 + w * 16 + (l & 15);
        const size_t qoffB = (size_t)(b * 2048 + qrowB) * 1024 + h * 64 + (l >> 4) * 8;
        qfhB[0] = *(const bfrag*)&qh[qoffB];
        qfhB[1] = *(const bfrag*)&qh[qoffB + 32];
        qflB[0] = f8frag(*(const uint2*)&ql8[qoffB]);
        qflB[1] = f8frag(*(const uint2*)&ql8[qoffB + 32]);
    }

    facc OA[4], OB[4], OsA, OsB;
    float mA[4], mB[4];
    #pragma unroll
    for (int f = 0; f < 4; ++f) { OA[f] = (facc)(0.0f); OB[f] = (facc)(0.0f); }
    OsA = (facc)(0.0f); OsB = (facc)(0.0f);
    #pragma unroll
    for (int r = 0; r < 4; ++r) { mA[r] = -1e30f; mB[r] = -1e30f; }

    stage_kv(kh, kl, vT, Kh[0], Kl[0], Vt[0], w, l, b, h, 0);
    for (int kt = 0; kt <= qtA; ++kt) {
        const int cur = kt & 1;
        __syncthreads();                   // drains my prior stage; WAR-protects buf
        if (kt < qtA)
            stage_kv(kh, kl, vT, Kh[cur ^ 1], Kl[cur ^ 1], Vt[cur ^ 1], w, l, b, h, kt + 1);
        __builtin_amdgcn_sched_barrier(0);
        __builtin_amdgcn_s_barrier();      // raw: prefetch stays in flight
        __builtin_amdgcn_sched_barrier(0);
        attn_step(Kh[cur], Kl[cur], Vt[cur], Pl, qfhA, qflA, OA, OsA, mA, ones,
                  w, l, kt == qtA);
        if (kt <= qtB)
            attn_step(Kh[cur], Kl[cur], Vt[cur], Pl, qfhB, qflB, OB, OsB, mB, ones,
                      w, l, kt == qtB);
    }

    #pragma unroll
    for (int f = 0; f < 4; ++f) {
        int d = h * 64 + f * 16 + (l & 15);
        #pragma unroll
        for (int r = 0; r < 4; ++r) {
            int tA = qtA * 64 + w * 16 + (l >> 4) * 4 + r;
            att[(size_t)(b * 2048 + tA) * 1024 + d] = f2bh(OA[f][r] / OsA[r]);
            int tB = qtB * 64 + w * 16 + (l >> 4) * 4 + r;
            att[(size_t)(b * 2048 + tB) * 1024 + d] = f2bh(OB[f][r] / OsB[r]);
        }
    }
}

// ---------------------------------------------------------------------------
// outproj: out[4096,1024] = att @ Wo^T.  BK=64 swizzled, double-buffered with
// the prefetch-across-raw-barrier loop.  grid (32, 8), 64KB LDS.
// ---------------------------------------------------------------------------
__global__ __launch_bounds__(256, 2) void outproj(
    const unsigned short* __restrict__ att, const unsigned short* __restrict__ WoB,
    float* __restrict__ out)
{
    __shared__ unsigned short Ab[2][128 * 64], Bb[2][128 * 64];
    const int tid = threadIdx.x, w = tid >> 6, l = tid & 63;
    const int wm = w >> 1, wn = w & 1;
    const int rt = blockIdx.x, ct = blockIdx.y;

    const int lc = (l & 7) ^ (l >> 3);         // logical chunk (0..7) -> k-offset lc*8
    facc acc[4][4];
    #pragma unroll
    for (int i = 0; i < 4; ++i)
        #pragma unroll
        for (int j = 0; j < 4; ++j) acc[i][j] = (facc)(0.0f);

    auto stage = [&](int buf, int e0) {
        #pragma unroll
        for (int i = 0; i < 4; ++i) {
            int slice = w * 4 + i;
            int row = slice * 8 + (l >> 3);
            gl_lds16(&att[(size_t)(rt * 128 + row) * 1024 + e0 + lc * 8], &Ab[buf][slice * 512]);
            gl_lds16(&WoB[(size_t)(ct * 128 + row) * 1024 + e0 + lc * 8], &Bb[buf][slice * 512]);
        }
    };

    stage(0, 0);
    int cur = 0;
    for (int t = 0; t < 16; ++t) {
        __syncthreads();
        if (t < 15) stage(cur ^ 1, (t + 1) * 64);
        __builtin_amdgcn_sched_barrier(0);
        __builtin_amdgcn_s_barrier();
        __builtin_amdgcn_sched_barrier(0);
        #pragma unroll
        for (int s = 0; s < 2; ++s) {
            const int slot = (s * 4 + (l >> 4)) ^ (l & 7);
            bfrag af[4], bf_[4];
            #pragma unroll
            for (int m = 0; m < 4; ++m)
                af[m] = *(const bfrag*)&Ab[cur][(wm * 64 + m * 16 + (l & 15)) * 64 + slot * 8];
            #pragma unroll
            for (int n = 0; n < 4; ++n)
                bf_[n] = *(const bfrag*)&Bb[cur][(wn * 64 + n * 16 + (l & 15)) * 64 + slot * 8];
            #pragma unroll
            for (int m = 0; m < 4; ++m)
                #pragma unroll
                for (int n = 0; n < 4; ++n)
                    acc[m][n] = MFMA(af[m], bf_[n], acc[m][n]);
        }
        cur ^= 1;
    }
    #pragma unroll
    for (int m = 0; m < 4; ++m)
        #pragma unroll
        for (int r = 0; r < 4; ++r) {
            int row = rt * 128 + wm * 64 + m * 16 + (l >> 4) * 4 + r;
            #pragma unroll
            for (int n = 0; n < 4; ++n) {
                int col = ct * 128 + wn * 64 + n * 16 + (l & 15);
                out[(size_t)row * 1024 + col] = acc[m][n][r];
            }
        }
}

// ---------------------------------------------------------------------------
extern "C" void kernel_launch(void* const* d_in, const int* in_sizes, int n_in,
                              void* d_out, int out_size, void* d_ws, size_t ws_size,
                              hipStream_t stream) {
    const float* x  = (const float*)d_in[0];
    // d_in[1]: causal mask (applied analytically)
    const float* Wq = (const float*)d_in[2];
    const float* Wk = (const float*)d_in[3];
    const float* Wv = (const float*)d_in[4];
    const float* Wo = (const float*)d_in[5];

    uint8_t* wsb = (uint8_t*)d_ws;
    const size_t MB = 1024 * 1024;
    // 64MB layout.  xh overlays att (xh dead before attn writes att).
    unsigned short* WqTh = (unsigned short*)(wsb + 0 * MB);
    unsigned short* WqTl = (unsigned short*)(wsb + 2 * MB);
    unsigned short* WkTh = (unsigned short*)(wsb + 4 * MB);
    unsigned short* WkTl = (unsigned short*)(wsb + 6 * MB);
    unsigned short* WvT  = (unsigned short*)(wsb + 8 * MB);
    unsigned short* qh   = (unsigned short*)(wsb + 10 * MB);  // 8MB
    unsigned char*  ql8  = (unsigned char*)(wsb + 18 * MB);   // 4MB fp8
    unsigned short* kh   = (unsigned short*)(wsb + 22 * MB);  // 8MB
    unsigned short* kl   = (unsigned short*)(wsb + 30 * MB);  // 8MB
    unsigned short* vT   = (unsigned short*)(wsb + 38 * MB);  // 8MB
    unsigned short* att  = (unsigned short*)(wsb + 46 * MB);  // 8MB
    unsigned short* xh   = (unsigned short*)(wsb + 46 * MB);  // 8MB (alias att)
    unsigned short* WoB  = (unsigned short*)(wsb + 54 * MB);  // 2MB
    unsigned short* xl   = (unsigned short*)(wsb + 56 * MB);  // 8MB

    hipFuncSetAttribute((const void*)qkv_fused,
                        hipFuncAttributeMaxDynamicSharedMemorySize, 73728);

    prep_xw<<<dim3(5120), 256, 0, stream>>>(x, Wo, xh, xl, WoB);
    prep_w<<<dim3(16, 16, 3), 256, 0, stream>>>(Wq, Wk, Wv, WqTh, WqTl, WkTh, WkTl, WvT);
    qkv_fused<<<dim3(16, 32), 256, 73728, stream>>>(xh, xl, WqTh, WqTl, WkTh, WkTl, WvT,
                                                    qh, ql8, kh, kl, vT);
    attn_mfma<<<dim3(16, 32), 256, 0, stream>>>(qh, ql8, kh, kl, vT, att);
    outproj<<<dim3(32, 8), 256, 0, stream>>>(att, WoB, (float*)d_out);
}

// Round 12
// 156.604 us; speedup vs baseline: 2.5212x; 1.0507x over previous
//
#include <hip/hip_runtime.h>
#include <hip/hip_fp8.h>
#include <stdint.h>

// (B,T,E,H,D) = (2,2048,1024,16,64)
constexpr float INV_SCALE = 0.022097086912079608f;  // 1/sqrt(2048)
constexpr float LOG2E = 1.4426950408889634f;
constexpr float QSC = INV_SCALE * LOG2E;            // q pre-scale: softmax in exp2 domain

typedef __attribute__((ext_vector_type(8))) short bfrag;          // 8 bf16 (4 VGPR) MFMA frag
typedef __attribute__((ext_vector_type(4))) float facc;           // 4 f32 MFMA acc
typedef __attribute__((ext_vector_type(4))) unsigned short us4;   // 4 bf16 = 8B

#define MFMA(a, b, c) __builtin_amdgcn_mfma_f32_16x16x32_bf16((a), (b), (c), 0, 0, 0)
#define EXP2(x) __builtin_amdgcn_exp2f(x)

__device__ __forceinline__ unsigned short f2bh(float f) {        // f32 -> bf16 RNE
    union { float f; unsigned int u; } cv; cv.f = f;
    unsigned int u = cv.u;
    u += 0x7FFFu + ((u >> 16) & 1u);
    return (unsigned short)(u >> 16);
}
__device__ __forceinline__ float bh2f(unsigned short h) {
    union { unsigned int u; float f; } cv; cv.u = ((unsigned int)h) << 16;
    return cv.f;
}
__device__ __forceinline__ void gl_lds16(const unsigned short* g, unsigned short* lds) {
    // async 16B/lane global->LDS; dst is wave-uniform base, lane i lands at dst+16*i
    __builtin_amdgcn_global_load_lds(
        (const __attribute__((address_space(1))) unsigned int*)g,
        (__attribute__((address_space(3))) unsigned int*)lds, 16, 0, 0);
}
// 8 fp8(e4m3, x256) bytes -> bf16 frag (undo the 256x scale)
__device__ __forceinline__ bfrag f8frag(uint2 raw) {
    union { uint2 u; unsigned char b[8]; } cv; cv.u = raw;
    bfrag r;
    #pragma unroll
    for (int j = 0; j < 8; ++j) {
        const __hip_fp8_e4m3* t = reinterpret_cast<const __hip_fp8_e4m3*>(&cv.b[j]);
        r[j] = (short)f2bh((float)(*t) * 0.00390625f);
    }
    return r;
}
// one DPP max-reduce stage over the 16-lane row (pure VALU, no LDS)
template<int CTRL>
__device__ __forceinline__ float dppmax(float v) {
    int s = __builtin_amdgcn_update_dpp(0, __builtin_bit_cast(int, v), CTRL, 0xF, 0xF, true);
    return fmaxf(v, __builtin_bit_cast(float, s));
}
__device__ __forceinline__ float rowmax16(float v) {
    v = dppmax<0xB1>(v);    // quad_perm [1,0,3,2]  (xor 1)
    v = dppmax<0x4E>(v);    // quad_perm [2,3,0,1]  (xor 2)
    v = dppmax<0x141>(v);   // row_half_mirror      (covers xor 4)
    v = dppmax<0x140>(v);   // row_mirror           (covers xor 8)
    return v;
}

// ---------------------------------------------------------------------------
// prep_xw: fused  Wo fp32->bf16 (blocks 0..1023)  +  x fp32->hi/lo split
// (blocks 1024..5119).
// ---------------------------------------------------------------------------
__global__ __launch_bounds__(256) void prep_xw(const float* __restrict__ x,
                                               const float* __restrict__ Wo,
                                               unsigned short* __restrict__ xh,
                                               unsigned short* __restrict__ xl,
                                               unsigned short* __restrict__ WoB) {
    if (blockIdx.x < 1024) {
        int idx = blockIdx.x * 256 + threadIdx.x;   // f4 index, 262144 total
        facc v = *(const facc*)&Wo[(size_t)idx * 4];
        us4 o;
        #pragma unroll
        for (int j = 0; j < 4; ++j) o[j] = f2bh(v[j]);
        *(us4*)&WoB[(size_t)idx * 4] = o;
    } else {
        int idx = (blockIdx.x - 1024) * 256 + threadIdx.x;  // f4 idx, 1,048,576 total
        facc v = *(const facc*)&x[(size_t)idx * 4];
        us4 hv, lv;
        #pragma unroll
        for (int j = 0; j < 4; ++j) {
            unsigned short hb = f2bh(v[j]);
            hv[j] = hb;
            lv[j] = f2bh(v[j] - bh2f(hb));
        }
        *(us4*)&xh[(size_t)idx * 4] = hv;
        *(us4*)&xl[(size_t)idx * 4] = lv;
    }
}

// ---------------------------------------------------------------------------
// prep_w: per head, transpose W[h][1024 e][64 i] -> WT[h*64+i][1024 e] with
// hi/lo bf16 split for Wq/Wk, hi-only for Wv.  grid (16,16,3), block 256.
// ---------------------------------------------------------------------------
__global__ __launch_bounds__(256) void prep_w(
    const float* __restrict__ Wq, const float* __restrict__ Wk, const float* __restrict__ Wv,
    unsigned short* __restrict__ WqTh, unsigned short* __restrict__ WqTl,
    unsigned short* __restrict__ WkTh, unsigned short* __restrict__ WkTl,
    unsigned short* __restrict__ WvT)
{
    __shared__ float tile[64][65];
    const int tid = threadIdx.x;
    const int et = blockIdx.x, h = blockIdx.y, m = blockIdx.z;
    const float* W = (m == 0) ? Wq : (m == 1) ? Wk : Wv;
    #pragma unroll
    for (int rep = 0; rep < 4; ++rep) {
        int idx = rep * 256 + tid;            // f4 idx over [64e][16 i4]
        int e = idx >> 4, i4 = (idx & 15) * 4;
        facc v = *(const facc*)&W[(size_t)h * 65536 + (size_t)(et * 64 + e) * 64 + i4];
        tile[e][i4] = v.x; tile[e][i4 + 1] = v.y; tile[e][i4 + 2] = v.z; tile[e][i4 + 3] = v.w;
    }
    __syncthreads();
    unsigned short* Oh = (m == 0) ? WqTh : (m == 1) ? WkTh : WvT;
    unsigned short* Ol = (m == 0) ? WqTl : WkTl;   // unused when m==2
    #pragma unroll
    for (int rep = 0; rep < 4; ++rep) {
        int idx = rep * 256 + tid;            // [64 i][16 e4]
        int i = idx >> 4, e4 = (idx & 15) * 4;
        us4 hv, lv;
        #pragma unroll
        for (int j = 0; j < 4; ++j) {
            float f = tile[e4 + j][i];
            unsigned short hb = f2bh(f);
            hv[j] = hb;
            lv[j] = f2bh(f - bh2f(hb));
        }
        size_t o = (size_t)(h * 64 + i) * 1024 + et * 64 + e4;
        *(us4*)&Oh[o] = hv;
        if (m < 2) *(us4*)&Ol[o] = lv;
    }
}

// ---------------------------------------------------------------------------
// qkv_fused: block (ct, rt) computes q,k,v for rows [rt*128,+128), cols
// [ct*64,+64) in one K=1024 pass.  256 threads (4 waves, 2x2).  72KB dynamic
// LDS -> 2 blocks/CU (two independent barrier domains).  Counted-vmcnt
// pipeline (vmcnt(9)).  grid (16 ct, 32 rt) = 512 blocks = 2/CU exact.
// ---------------------------------------------------------------------------
__global__ __launch_bounds__(256, 2) void qkv_fused(
    const unsigned short* __restrict__ xh, const unsigned short* __restrict__ xl,
    const unsigned short* __restrict__ WqTh, const unsigned short* __restrict__ WqTl,
    const unsigned short* __restrict__ WkTh, const unsigned short* __restrict__ WkTl,
    const unsigned short* __restrict__ WvT,
    unsigned short* __restrict__ qh, unsigned char* __restrict__ ql8,
    unsigned short* __restrict__ kh, unsigned short* __restrict__ kl,
    unsigned short* __restrict__ vT)
{
    extern __shared__ unsigned short sm[];
    unsigned short* Ab = sm;               // [2][128*64] 32KB (x hi|lo, XOR-8 swz)
    unsigned short* Qb = sm + 16384;       // [2][64*64] 16KB
    unsigned short* Kb = sm + 24576;       // [2][64*64] 16KB
    unsigned short* Vb = sm + 32768;       // [2][64*32] 8KB  ((row>>1)&3 swz)
    const int tid = threadIdx.x;
    const int w = tid >> 6, l = tid & 63;
    const int wm = w >> 1, wn = w & 1;     // 2 x 2 wave grid
    const int ct = blockIdx.x, rt = blockIdx.y;

    const int lc = (l & 7) ^ (l >> 3);     // logical chunk at dest (128B rows)
    const int krel = (lc & 3) * 8;
    const unsigned short* Axp = (lc < 4) ? xh : xl;
    const unsigned short* Qp  = (lc < 4) ? WqTh : WqTl;
    const unsigned short* Kp  = (lc < 4) ? WkTh : WkTl;
    const int lcv = (l & 3) ^ ((l >> 3) & 3);   // V logical chunk (64B rows)

    facc accq[4][2], acck[4][2], accv[4][2];
    #pragma unroll
    for (int m = 0; m < 4; ++m)
        #pragma unroll
        for (int n = 0; n < 2; ++n) {
            accq[m][n] = (facc)(0.0f); acck[m][n] = (facc)(0.0f); accv[m][n] = (facc)(0.0f);
        }

    auto stageV = [&](int buf, int e0) {
        int row = w * 16 + (l >> 2);
        gl_lds16(&WvT[(size_t)(ct * 64 + row) * 1024 + e0 + lcv * 8],
                 &Vb[buf * 2048 + w * 512]);
    };

    // prologue: step 0
    {
        #pragma unroll
        for (int i = 0; i < 4; ++i) {
            int slice = w * 4 + i;
            int row = slice * 8 + (l >> 3);
            gl_lds16(&Axp[(size_t)(rt * 128 + row) * 1024 + krel], &Ab[slice * 512]);
        }
        #pragma unroll
        for (int i = 0; i < 2; ++i) {
            int slice = w * 2 + i;
            int row = slice * 8 + (l >> 3);
            size_t sb = (size_t)(ct * 64 + row) * 1024 + krel;
            gl_lds16(&Qp[sb], &Qb[slice * 512]);
            gl_lds16(&Kp[sb], &Kb[slice * 512]);
        }
        stageV(0, 0);
    }
    asm volatile("s_waitcnt vmcnt(0)" ::: "memory");
    __builtin_amdgcn_s_barrier();

    for (int t = 0; t < 32; ++t) {
        __builtin_amdgcn_s_barrier();              // bar1: all done with t-1 compute
        __builtin_amdgcn_sched_barrier(0);
        if (t < 31) {
            int buf = (t + 1) & 1, e0 = (t + 1) * 32;
            #pragma unroll
            for (int i = 0; i < 4; ++i) {
                int slice = w * 4 + i;
                int row = slice * 8 + (l >> 3);
                gl_lds16(&Axp[(size_t)(rt * 128 + row) * 1024 + e0 + krel],
                         &Ab[buf * 8192 + slice * 512]);
            }
            #pragma unroll
            for (int i = 0; i < 2; ++i) {
                int slice = w * 2 + i;
                int row = slice * 8 + (l >> 3);
                size_t sb = (size_t)(ct * 64 + row) * 1024 + e0 + krel;
                gl_lds16(&Qp[sb], &Qb[buf * 4096 + slice * 512]);
                gl_lds16(&Kp[sb], &Kb[buf * 4096 + slice * 512]);
            }
            stageV(buf, e0);
        }
        __builtin_amdgcn_sched_barrier(0);
        if (t < 31) asm volatile("s_waitcnt vmcnt(9)" ::: "memory");
        else        asm volatile("s_waitcnt vmcnt(0)" ::: "memory");
        __builtin_amdgcn_sched_barrier(0);
        __builtin_amdgcn_s_barrier();              // bar2: everyone's cur loads landed
        __builtin_amdgcn_sched_barrier(0);

        const unsigned short* Ac = &Ab[(t & 1) * 8192];
        const unsigned short* Qc = &Qb[(t & 1) * 4096];
        const unsigned short* Kc = &Kb[(t & 1) * 4096];
        const unsigned short* Vc = &Vb[(t & 1) * 2048];
        const int ca = (l >> 4) ^ (l & 7);         // phys chunk of hi frag (128B rows)
        const int cb = ca ^ 4;                     // lo frag

        bfrag afh[4], afl[4];
        #pragma unroll
        for (int m = 0; m < 4; ++m) {
            int row = wm * 64 + m * 16 + (l & 15);
            afh[m] = *(const bfrag*)&Ac[row * 64 + ca * 8];
            afl[m] = *(const bfrag*)&Ac[row * 64 + cb * 8];
        }
        #pragma unroll
        for (int n = 0; n < 2; ++n) {
            int nr = wn * 32 + n * 16 + (l & 15);
            int cv = (l >> 4) ^ ((nr >> 1) & 3);   // V phys chunk (64B rows)
            bfrag bv = *(const bfrag*)&Vc[nr * 32 + cv * 8];
            #pragma unroll
            for (int m = 0; m < 4; ++m) accv[m][n] = MFMA(afh[m], bv, accv[m][n]);
        }
        #pragma unroll
        for (int n = 0; n < 2; ++n) {
            int nr = wn * 32 + n * 16 + (l & 15);
            bfrag bh = *(const bfrag*)&Qc[nr * 64 + ca * 8];
            bfrag bl = *(const bfrag*)&Qc[nr * 64 + cb * 8];
            #pragma unroll
            for (int m = 0; m < 4; ++m) {
                accq[m][n] = MFMA(afh[m], bh, accq[m][n]);
                accq[m][n] = MFMA(afh[m], bl, accq[m][n]);
                accq[m][n] = MFMA(afl[m], bh, accq[m][n]);
            }
        }
        #pragma unroll
        for (int n = 0; n < 2; ++n) {
            int nr = wn * 32 + n * 16 + (l & 15);
            bfrag bh = *(const bfrag*)&Kc[nr * 64 + ca * 8];
            bfrag bl = *(const bfrag*)&Kc[nr * 64 + cb * 8];
            #pragma unroll
            for (int m = 0; m < 4; ++m) {
                acck[m][n] = MFMA(afh[m], bh, acck[m][n]);
                acck[m][n] = MFMA(afh[m], bl, acck[m][n]);
                acck[m][n] = MFMA(afl[m], bh, acck[m][n]);
            }
        }
    }

    // epilogue
    #pragma unroll
    for (int m = 0; m < 4; ++m)
        #pragma unroll
        for (int r = 0; r < 4; ++r) {
            int row = rt * 128 + wm * 64 + m * 16 + (l >> 4) * 4 + r;
            #pragma unroll
            for (int n = 0; n < 2; ++n) {
                int col = ct * 64 + wn * 32 + n * 16 + (l & 15);
                float fq = accq[m][n][r] * QSC;
                unsigned short hb = f2bh(fq);
                qh[(size_t)row * 1024 + col] = hb;
                __hip_fp8_e4m3 e((fq - bh2f(hb)) * 256.0f);
                ql8[(size_t)row * 1024 + col] = *reinterpret_cast<unsigned char*>(&e);
                float fk = acck[m][n][r];
                unsigned short kb = f2bh(fk);
                kh[(size_t)row * 1024 + col] = kb;
                kl[(size_t)row * 1024 + col] = f2bh(fk - bh2f(kb));
            }
        }
    // v: write transposed vT[(h*2+b)*64 + d][t], pack 4 consecutive t
    #pragma unroll
    for (int m = 0; m < 4; ++m) {
        int t0g = rt * 128 + wm * 64 + m * 16 + (l >> 4) * 4;
        int b_ = t0g >> 11, t0 = t0g & 2047;
        #pragma unroll
        for (int n = 0; n < 2; ++n) {
            int col = ct * 64 + wn * 32 + n * 16 + (l & 15);
            int h_ = col >> 6, d = col & 63;
            us4 pk;
            #pragma unroll
            for (int r = 0; r < 4; ++r) pk[r] = f2bh(accv[m][n][r]);
            *(us4*)&vT[((size_t)((h_ * 2 + b_) * 64 + d)) * 2048 + t0] = pk;
        }
    }
}

// ---------------------------------------------------------------------------
// attn helpers
// ---------------------------------------------------------------------------
__device__ __forceinline__ void stage_k(
    const unsigned short* __restrict__ kh, const unsigned short* __restrict__ kl,
    unsigned short* Khb, unsigned short* Klb, int w, int l, int b, int h, int kt)
{
    #pragma unroll
    for (int i = 0; i < 2; ++i) {
        int pbase = (w * 2 + i) * 1024;    // uniform 1KB slice base (bytes)
        int p = pbase + l * 16;
        int row = p >> 7, slot = (p >> 4) & 7;
        int chunk = slot ^ (row & 7);      // inverse-swizzled source chunk
        size_t srcK = (size_t)(b * 2048 + kt * 64 + row) * 1024 + h * 64 + chunk * 8;
        gl_lds16(&kh[srcK], &Khb[pbase >> 1]);
        gl_lds16(&kl[srcK], &Klb[pbase >> 1]);
    }
}
__device__ __forceinline__ void stage_v(
    const unsigned short* __restrict__ vT, unsigned short* Vtb,
    int w, int l, int b, int h, int kt)
{
    #pragma unroll
    for (int i = 0; i < 2; ++i) {
        int pbase = (w * 2 + i) * 1024;
        int p = pbase + l * 16;
        int row = p >> 7, slot = (p >> 4) & 7;
        int chunk = slot ^ (row & 7);
        size_t srcV = ((size_t)(h * 2 + b) * 64 + row) * 2048 + (size_t)kt * 64 + chunk * 8;
        gl_lds16(&vT[srcV], &Vtb[pbase >> 1]);
    }
}

// ---------------------------------------------------------------------------
// attn_mfma: de-paired single-tile flash attention.  grid (32, 32) = 1024
// blocks (one 64-row q-tile each), 4 waves, 48KB static LDS -> 3 blocks/CU.
// qt-major DESCENDING dispatch order (longest blocks first) lets the HW
// scheduler backfill the causal imbalance.  K double-buffered (prefetch
// across raw barrier); V single-buffered just-in-time: staged at iter top,
// drained by counted vmcnt(4) + raw barrier before PV.
// ---------------------------------------------------------------------------
__global__ __launch_bounds__(256, 3) void attn_mfma(
    const unsigned short* __restrict__ qh, const unsigned char* __restrict__ ql8,
    const unsigned short* __restrict__ kh, const unsigned short* __restrict__ kl,
    const unsigned short* __restrict__ vT, unsigned short* __restrict__ att)
{
    __shared__ unsigned short Kh[2][4096], Kl[2][4096], Vt[4096], Pl[4096];
    const int tid = threadIdx.x, w = tid >> 6, l = tid & 63;
    // dd ascending = dispatch order.  qt-major descending; XCD-striped hb.
    const int dd = blockIdx.y * 32 + blockIdx.x;
    const int xcd = dd & 7, sl = dd >> 3;          // sl in 0..127
    const int qt = 31 - (sl >> 2);                 // first dispatched = qt 31
    const int hb = xcd * 4 + (sl & 3);             // 4 hb per XCD (K/V L2-resident)
    const int h = hb >> 1, b = hb & 1;

    bfrag ones;
    #pragma unroll
    for (int j = 0; j < 8; ++j) ones[j] = (short)0x3F80;   // bf16 1.0

    bfrag qfh[2], qfl[2];
    {
        const int qrow = qt * 64 + w * 16 + (l & 15);
        const size_t qoff = (size_t)(b * 2048 + qrow) * 1024 + h * 64 + (l >> 4) * 8;
        qfh[0] = *(const bfrag*)&qh[qoff];
        qfh[1] = *(const bfrag*)&qh[qoff + 32];
        qfl[0] = f8frag(*(const uint2*)&ql8[qoff]);
        qfl[1] = f8frag(*(const uint2*)&ql8[qoff + 32]);
    }

    facc O[4], Osum;
    float mrow[4];
    #pragma unroll
    for (int f = 0; f < 4; ++f) O[f] = (facc)(0.0f);
    Osum = (facc)(0.0f);
    #pragma unroll
    for (int r = 0; r < 4; ++r) mrow[r] = -1e30f;

    stage_k(kh, kl, Kh[0], Kl[0], w, l, b, h, 0);
    for (int kt = 0; kt <= qt; ++kt) {
        const int cur = kt & 1;
        __syncthreads();                   // drains prior loads; WAR on K^1 and Vt
        stage_v(vT, Vt, w, l, b, h, kt);   // just-in-time V (2 loads)
        if (kt < qt)
            stage_k(kh, kl, Kh[cur ^ 1], Kl[cur ^ 1], w, l, b, h, kt + 1);  // 4 loads
        __builtin_amdgcn_sched_barrier(0);
        __builtin_amdgcn_s_barrier();      // all waves past their drain -> K[cur] valid
        __builtin_amdgcn_sched_barrier(0);

        // ---- QK^T (split 3-term) ----
        facc S[4];
        #pragma unroll
        for (int f = 0; f < 4; ++f) S[f] = (facc)(0.0f);
        __builtin_amdgcn_s_setprio(1);
        #pragma unroll
        for (int s = 0; s < 2; ++s) {
            #pragma unroll
            for (int f = 0; f < 4; ++f) {
                int key = f * 16 + (l & 15);
                int ch = (s * 4 + (l >> 4)) ^ (key & 7);
                bfrag kbh = *(const bfrag*)&Kh[cur][key * 64 + ch * 8];
                bfrag kbl = *(const bfrag*)&Kl[cur][key * 64 + ch * 8];
                S[f] = MFMA(qfh[s], kbh, S[f]);
                S[f] = MFMA(qfh[s], kbl, S[f]);
                S[f] = MFMA(qfl[s], kbh, S[f]);
            }
        }
        __builtin_amdgcn_s_setprio(0);
        if (kt == qt) {                    // causal mask on diagonal tile
            #pragma unroll
            for (int f = 0; f < 4; ++f) {
                int keyl = f * 16 + (l & 15);
                #pragma unroll
                for (int r = 0; r < 4; ++r) {
                    int qls = w * 16 + (l >> 4) * 4 + r;
                    if (keyl > qls) S[f][r] = -1e30f;
                }
            }
        }
        // ---- softmax: DPP row-max, defer-max (THR=8), exp2 ----
        float mx[4];
        float dmax = -3.0e38f;
        #pragma unroll
        for (int r = 0; r < 4; ++r) {
            float m0 = fmaxf(fmaxf(S[0][r], S[1][r]), fmaxf(S[2][r], S[3][r]));
            m0 = rowmax16(m0);
            mx[r] = m0;
            dmax = fmaxf(dmax, m0 - mrow[r]);
        }
        if (!__all(dmax <= 8.0f)) {        // wave-uniform, rare after warmup
            #pragma unroll
            for (int r = 0; r < 4; ++r) {
                float mn = fmaxf(mrow[r], mx[r]);
                float fac = EXP2(mrow[r] - mn);
                mrow[r] = mn;
                O[0][r] *= fac; O[1][r] *= fac; O[2][r] *= fac; O[3][r] *= fac;
                Osum[r] *= fac;
            }
        }
        #pragma unroll
        for (int r = 0; r < 4; ++r)
            #pragma unroll
            for (int f = 0; f < 4; ++f) S[f][r] = EXP2(S[f][r] - mrow[r]);
        // P -> LDS (bf16, swizzled rows; same-wave rows only)
        #pragma unroll
        for (int f = 0; f < 4; ++f) {
            int key = f * 16 + (l & 15);
            #pragma unroll
            for (int r = 0; r < 4; ++r) {
                int qr = w * 16 + (l >> 4) * 4 + r;
                Pl[qr * 64 + (((key >> 3) ^ (qr & 7)) * 8) + (key & 7)] = f2bh(S[f][r]);
            }
        }
        // ---- drain my V loads (K prefetch stays in flight), then sync ----
        __builtin_amdgcn_sched_barrier(0);
        if (kt < qt) asm volatile("s_waitcnt vmcnt(4)" ::: "memory");
        else         asm volatile("s_waitcnt vmcnt(0)" ::: "memory");
        __builtin_amdgcn_sched_barrier(0);
        __builtin_amdgcn_s_barrier();      // every wave's V landed -> Vt valid
        __builtin_amdgcn_sched_barrier(0);
        // ---- PV + denominator via ones-MFMA ----
        __builtin_amdgcn_s_setprio(1);
        #pragma unroll
        for (int s = 0; s < 2; ++s) {
            int qa = w * 16 + (l & 15);
            int cha = (s * 4 + (l >> 4)) ^ (qa & 7);
            bfrag pa = *(const bfrag*)&Pl[qa * 64 + cha * 8];
            Osum = MFMA(pa, ones, Osum);
            #pragma unroll
            for (int f = 0; f < 4; ++f) {
                int d = f * 16 + (l & 15);
                int chv = (s * 4 + (l >> 4)) ^ (d & 7);
                bfrag vb = *(const bfrag*)&Vt[d * 64 + chv * 8];
                O[f] = MFMA(pa, vb, O[f]);
            }
        }
        __builtin_amdgcn_s_setprio(0);
    }

    #pragma unroll
    for (int f = 0; f < 4; ++f) {
        int d = h * 64 + f * 16 + (l & 15);
        #pragma unroll
        for (int r = 0; r < 4; ++r) {
            int t = qt * 64 + w * 16 + (l >> 4) * 4 + r;
            att[(size_t)(b * 2048 + t) * 1024 + d] = f2bh(O[f][r] / Osum[r]);
        }
    }
}

// ---------------------------------------------------------------------------
// outproj: out[4096,1024] = att @ Wo^T.  BK=64 swizzled, double-buffered with
// the prefetch-across-raw-barrier loop.  grid (32, 8), 64KB LDS.
// ---------------------------------------------------------------------------
__global__ __launch_bounds__(256, 2) void outproj(
    const unsigned short* __restrict__ att, const unsigned short* __restrict__ WoB,
    float* __restrict__ out)
{
    __shared__ unsigned short Ab[2][128 * 64], Bb[2][128 * 64];
    const int tid = threadIdx.x, w = tid >> 6, l = tid & 63;
    const int wm = w >> 1, wn = w & 1;
    const int rt = blockIdx.x, ct = blockIdx.y;

    const int lc = (l & 7) ^ (l >> 3);         // logical chunk (0..7) -> k-offset lc*8
    facc acc[4][4];
    #pragma unroll
    for (int i = 0; i < 4; ++i)
        #pragma unroll
        for (int j = 0; j < 4; ++j) acc[i][j] = (facc)(0.0f);

    auto stage = [&](int buf, int e0) {
        #pragma unroll
        for (int i = 0; i < 4; ++i) {
            int slice = w * 4 + i;
            int row = slice * 8 + (l >> 3);
            gl_lds16(&att[(size_t)(rt * 128 + row) * 1024 + e0 + lc * 8], &Ab[buf][slice * 512]);
            gl_lds16(&WoB[(size_t)(ct * 128 + row) * 1024 + e0 + lc * 8], &Bb[buf][slice * 512]);
        }
    };

    stage(0, 0);
    int cur = 0;
    for (int t = 0; t < 16; ++t) {
        __syncthreads();
        if (t < 15) stage(cur ^ 1, (t + 1) * 64);
        __builtin_amdgcn_sched_barrier(0);
        __builtin_amdgcn_s_barrier();
        __builtin_amdgcn_sched_barrier(0);
        #pragma unroll
        for (int s = 0; s < 2; ++s) {
            const int slot = (s * 4 + (l >> 4)) ^ (l & 7);
            bfrag af[4], bf_[4];
            #pragma unroll
            for (int m = 0; m < 4; ++m)
                af[m] = *(const bfrag*)&Ab[cur][(wm * 64 + m * 16 + (l & 15)) * 64 + slot * 8];
            #pragma unroll
            for (int n = 0; n < 4; ++n)
                bf_[n] = *(const bfrag*)&Bb[cur][(wn * 64 + n * 16 + (l & 15)) * 64 + slot * 8];
            #pragma unroll
            for (int m = 0; m < 4; ++m)
                #pragma unroll
                for (int n = 0; n < 4; ++n)
                    acc[m][n] = MFMA(af[m], bf_[n], acc[m][n]);
        }
        cur ^= 1;
    }
    #pragma unroll
    for (int m = 0; m < 4; ++m)
        #pragma unroll
        for (int r = 0; r < 4; ++r) {
            int row = rt * 128 + wm * 64 + m * 16 + (l >> 4) * 4 + r;
            #pragma unroll
            for (int n = 0; n < 4; ++n) {
                int col = ct * 128 + wn * 64 + n * 16 + (l & 15);
                out[(size_t)row * 1024 + col] = acc[m][n][r];
            }
        }
}

// ---------------------------------------------------------------------------
extern "C" void kernel_launch(void* const* d_in, const int* in_sizes, int n_in,
                              void* d_out, int out_size, void* d_ws, size_t ws_size,
                              hipStream_t stream) {
    const float* x  = (const float*)d_in[0];
    // d_in[1]: causal mask (applied analytically)
    const float* Wq = (const float*)d_in[2];
    const float* Wk = (const float*)d_in[3];
    const float* Wv = (const float*)d_in[4];
    const float* Wo = (const float*)d_in[5];

    uint8_t* wsb = (uint8_t*)d_ws;
    const size_t MB = 1024 * 1024;
    // 64MB layout.  xh overlays att (xh dead before attn writes att).
    unsigned short* WqTh = (unsigned short*)(wsb + 0 * MB);
    unsigned short* WqTl = (unsigned short*)(wsb + 2 * MB);
    unsigned short* WkTh = (unsigned short*)(wsb + 4 * MB);
    unsigned short* WkTl = (unsigned short*)(wsb + 6 * MB);
    unsigned short* WvT  = (unsigned short*)(wsb + 8 * MB);
    unsigned short* qh   = (unsigned short*)(wsb + 10 * MB);  // 8MB
    unsigned char*  ql8  = (unsigned char*)(wsb + 18 * MB);   // 4MB fp8
    unsigned short* kh   = (unsigned short*)(wsb + 22 * MB);  // 8MB
    unsigned short* kl   = (unsigned short*)(wsb + 30 * MB);  // 8MB
    unsigned short* vT   = (unsigned short*)(wsb + 38 * MB);  // 8MB
    unsigned short* att  = (unsigned short*)(wsb + 46 * MB);  // 8MB
    unsigned short* xh   = (unsigned short*)(wsb + 46 * MB);  // 8MB (alias att)
    unsigned short* WoB  = (unsigned short*)(wsb + 54 * MB);  // 2MB
    unsigned short* xl   = (unsigned short*)(wsb + 56 * MB);  // 8MB

    hipFuncSetAttribute((const void*)qkv_fused,
                        hipFuncAttributeMaxDynamicSharedMemorySize, 73728);

    prep_xw<<<dim3(5120), 256, 0, stream>>>(x, Wo, xh, xl, WoB);
    prep_w<<<dim3(16, 16, 3), 256, 0, stream>>>(Wq, Wk, Wv, WqTh, WqTl, WkTh, WkTl, WvT);
    qkv_fused<<<dim3(16, 32), 256, 73728, stream>>>(xh, xl, WqTh, WqTl, WkTh, WkTl, WvT,
                                                    qh, ql8, kh, kl, vT);
    attn_mfma<<<dim3(32, 32), 256, 0, stream>>>(qh, ql8, kh, kl, vT, att);
    outproj<<<dim3(32, 8), 256, 0, stream>>>(att, WoB, (float*)d_out);
}